// Round 7
// baseline (294.788 us; speedup 1.0000x reference)
//
#include <hip/hip_runtime.h>
#include <hip/hip_bf16.h>
#include <hip/hip_cooperative_groups.h>

namespace cg = cooperative_groups;

// ---------------------------------------------------------------------------
// MonotonicAlignmentSearch R19: cooperative mega-kernel, hardened.
// R18's failure signature (absmax == max|ref|, zeros) => coop launch was
// rejected and unchecked. Now: 256 blocks (1/CU guaranteed co-resident),
// __launch_bounds__(512,2) (VGPR<=256), grid-stride phase loops, and a
// host-side FALLBACK to the proven R16 4-kernel sequence (same device
// functions) if hipLaunchCooperativeKernel returns an error.
// B=2, TT=128, TA=512, H=1024.
// ---------------------------------------------------------------------------

typedef __bf16 bf16_t;
typedef __bf16 bf16x8 __attribute__((ext_vector_type(8)));
typedef __bf16 bf16x4 __attribute__((ext_vector_type(4)));
typedef float  f32x4  __attribute__((ext_vector_type(4)));
typedef _Float16 f16_t;
typedef _Float16 f16x2 __attribute__((ext_vector_type(2)));
typedef _Float16 f16x4 __attribute__((ext_vector_type(4)));

#define EPSV 1e-5f

#define OFF_TEXTBF   0u
#define OFF_AUDIOBF  524288u
#define OFF_W1TOP    2621440u
#define OFF_W1BOT    4718592u
#define OFF_WC1      6815744u
#define OFF_WC2      13107200u
#define OFF_TP       19398656u
#define OFF_W2F      19922944u
#define OFF_APT      20447232u
#define OFF_XP0      22544384u
#define OFF_XP1      23076864u
#define OFF_Y2       23609344u
#define OFF_BST1     24133632u
#define OFF_BST2     24137728u
#define OFF_LP       24141824u
#define OFF_SG       26238976u
#define OFF_SB       26251264u
#define OFF_SGF      26263552u
#define OFF_SBF      26267648u

struct KP {
    const float *text, *audio, *w1, *w1c, *w2c, *w2raw, *g1, *b1g;
    const float *db1, *ab1, *db2, *ab2, *g2, *bet2, *w3, *b3;
    bf16_t *text_bf, *audio_bf, *topT, *botT, *wc1, *wc2, *xp0, *xp1, *y2;
    f16_t *tp, *w2f, *apT4;
    float *bstat1, *bstat2, *lp, *Sg3, *Sb3, *SgF, *SbF;
    float *out;
};

__device__ __forceinline__ float wave_red_add(float v) {
    #pragma unroll
    for (int off = 32; off > 0; off >>= 1) v += __shfl_xor(v, off);
    return v;
}

// Per-wave conv K-slice (R16): wave w handles k in [w*128,+128) of each tap.
// 12 chunks as 2 straight-line segments of 18 independent loads.
__device__ __forceinline__ void conv_wave_partial(
    const bf16_t* __restrict__ Wc, const bf16_t* __restrict__ xp,
    int m0, int b, int tbase, int w, int l, f32x4& acc0, f32x4& acc1)
{
    const int lm = l & 15, lk = (l >> 4) * 8;
    const int koff = w * 128;
    const bf16_t* aq = Wc + (size_t)(m0 + lm) * 1024 + koff + lk;
    const bf16_t* bq = xp + (size_t)(b * 130 + tbase + lm) * 1024 + koff + lk;
    #pragma unroll
    for (int s = 0; s < 2; ++s) {
        bf16x8 ra[6], rb0[6], rb1[6];
        #pragma unroll
        for (int j = 0; j < 6; ++j) {
            const int idx = s * 6 + j;            // 0..11
            const int rr = idx >> 2, cc = idx & 3;
            const bf16_t* pa = aq + (size_t)rr * 1048576 + cc * 32;
            const bf16_t* pb = bq + (size_t)rr * 1024 + cc * 32;
            ra[j]  = *(const bf16x8*)pa;
            rb0[j] = *(const bf16x8*)pb;
            rb1[j] = *(const bf16x8*)(pb + 16384);
        }
        #pragma unroll
        for (int j = 0; j < 6; ++j) {
            acc0 = __builtin_amdgcn_mfma_f32_16x16x32_bf16(ra[j], rb0[j], acc0, 0, 0, 0);
            acc1 = __builtin_amdgcn_mfma_f32_16x16x32_bf16(ra[j], rb1[j], acc1, 0, 0, 0);
        }
    }
}

// reduce 256 (s,q) pairs for batch b (512 threads; contains one barrier).
__device__ __forceinline__ void reduce_bstat(
    const float* __restrict__ bstat, int b, int tid,
    float* sr, float* sq, float& mu, float& rsig)
{
    const int lane = tid & 63, wid = tid >> 6;
    float s = 0.f, q = 0.f;
    if (tid < 256) {
        float2 v = ((const float2*)bstat)[b * 256 + tid];
        s = v.x; q = v.y;
    }
    #pragma unroll
    for (int off = 32; off > 0; off >>= 1) {
        s += __shfl_xor(s, off);
        q += __shfl_xor(q, off);
    }
    if (lane == 0) { sr[wid] = s; sq[wid] = q; }
    __syncthreads();
    float ts = 0.f, tq = 0.f;
    #pragma unroll
    for (int i = 0; i < 8; ++i) { ts += sr[i]; tq += sq[i]; }
    const float cnt = 131072.f;
    mu = ts / cnt;
    const float var = tq / cnt - mu * mu;
    rsig = rsqrtf(var + EPSV);
}

__device__ __forceinline__ float dot2_acc(f16x2 x, f16x2 w, float acc) {
#if __has_builtin(__builtin_amdgcn_fdot2)
    return __builtin_amdgcn_fdot2(x, w, acc, false);
#else
    return acc + (float)x[0] * (float)w[0] + (float)x[1] * (float)w[1];
#endif
}

// ---------------------------------------------------------------------------
// prep unit (256-thread group, t in [0,256)); tile = 1056 floats.
// Stage boundaries 1280/3328/4352/5376 are even => unit pairs (2i,2i+1)
// always share identical barrier structure in the fused kernel.
// ---------------------------------------------------------------------------
__device__ void prep_unit(int u, int t, float* tile, const KP& p)
{
    if (u < 1280) {
        const int e = (u * 256 + t) * 4;
        if (e < 262144) {
            float4 v = *(const float4*)&p.text[e];
            bf16x4 o; o[0] = (bf16_t)v.x; o[1] = (bf16_t)v.y; o[2] = (bf16_t)v.z; o[3] = (bf16_t)v.w;
            *(bf16x4*)&p.text_bf[e] = o;
            const int bt = e >> 10, h = e & 1023;
            const int b = bt >> 7, tt = bt & 127;
            *(bf16x4*)&p.xp0[(size_t)(b * 130 + 1 + tt) * 1024 + h] = o;
        } else {
            const int ea = e - 262144;
            float4 v = *(const float4*)&p.audio[ea];
            bf16x4 o; o[0] = (bf16_t)v.x; o[1] = (bf16_t)v.y; o[2] = (bf16_t)v.z; o[3] = (bf16_t)v.w;
            *(bf16x4*)&p.audio_bf[ea] = o;
        }
    } else if (u < 3328) {
        const int b2 = u - 1280;
        const int bx = b2 & 31, by = b2 >> 5;
        const int tx = t & 31, ty = t >> 5;
        #pragma unroll
        for (int j = 0; j < 4; ++j)
            tile[(ty + j * 8) * 33 + tx] = p.w1[(size_t)(by * 32 + ty + j * 8) * 1024 + bx * 32 + tx];
        __syncthreads();
        bf16_t* out = (by < 32) ? p.topT : p.botT;
        const int hbase = (by & 31) * 32;
        #pragma unroll
        for (int j = 0; j < 4; ++j) {
            const int d = bx * 32 + ty + j * 8;
            out[(size_t)d * 1024 + hbase + tx] = (bf16_t)tile[tx * 33 + ty + j * 8];
        }
    } else if (u < 5376) {
        int b2 = u - 3328;
        const int is2 = (b2 >= 1024) ? 1 : 0;
        const float* wsrc = is2 ? p.w2c : p.w1c;
        bf16_t* wc = is2 ? p.wc2 : p.wc1;
        b2 &= 1023;
        const int o = b2, i4 = t;
        const float* src = wsrc + (size_t)o * 3072 + i4 * 12;
        float4 v0 = *(const float4*)&src[0];
        float4 v1 = *(const float4*)&src[4];
        float4 v2 = *(const float4*)&src[8];
        const float f[12] = {v0.x, v0.y, v0.z, v0.w, v1.x, v1.y, v1.z, v1.w, v2.x, v2.y, v2.z, v2.w};
        float g4[4] = {1.f, 1.f, 1.f, 1.f}, bb4[4] = {0.f, 0.f, 0.f, 0.f};
        if (is2) {
            float4 gv = *(const float4*)&p.g1[i4 * 4];
            float4 bv = *(const float4*)&p.b1g[i4 * 4];
            g4[0] = gv.x; g4[1] = gv.y; g4[2] = gv.z; g4[3] = gv.w;
            bb4[0] = bv.x; bb4[1] = bv.y; bb4[2] = bv.z; bb4[3] = bv.w;
        }
        float sgr[3] = {0.f, 0.f, 0.f}, sbr[3] = {0.f, 0.f, 0.f};
        #pragma unroll
        for (int r = 0; r < 3; ++r) {
            bf16x4 o4;
            #pragma unroll
            for (int j = 0; j < 4; ++j) {
                const float wv = f[j * 3 + r];
                const float ws = wv * g4[j];
                sgr[r] += ws;
                sbr[r] += wv * bb4[j];
                o4[j] = (bf16_t)(is2 ? ws : wv);
            }
            *(bf16x4*)&wc[(size_t)r * 1048576 + (size_t)o * 1024 + i4 * 4] = o4;
        }
        if (is2) {
            #pragma unroll
            for (int off = 32; off > 0; off >>= 1) {
                #pragma unroll
                for (int r = 0; r < 3; ++r) {
                    sgr[r] += __shfl_xor(sgr[r], off);
                    sbr[r] += __shfl_xor(sbr[r], off);
                }
            }
            float* red = tile;
            const int wid = t >> 6, lane = t & 63;
            if (lane == 0) {
                #pragma unroll
                for (int r = 0; r < 3; ++r) {
                    red[wid * 6 + r] = sgr[r];
                    red[wid * 6 + 3 + r] = sbr[r];
                }
            }
            __syncthreads();
            if (t < 6) {
                const float v = red[t] + red[6 + t] + red[12 + t] + red[18 + t];
                if (t < 3) p.Sg3[o * 3 + t] = v;
                else       p.Sb3[o * 3 + t - 3] = v;
                red[24 + t] = v;
            }
            __syncthreads();
            if (t == 0)      p.SgF[o] = red[24] + red[25] + red[26];
            else if (t == 1) p.SbF[o] = red[27] + red[28] + red[29];
        }
    } else {
        const int rowmap[4] = {0, 129, 130, 259};
        const int f = t * 16;
        const int r = f >> 10, ww = f & 1023;
        bf16x8 z8 = (bf16x8)(bf16_t)0.0f;
        bf16_t* p0 = p.xp0 + (size_t)rowmap[r] * 1024 + ww;
        bf16_t* p1 = p.xp1 + (size_t)rowmap[r] * 1024 + ww;
        *(bf16x8*)p0 = z8; *(bf16x8*)(p0 + 8) = z8;
        *(bf16x8*)p1 = z8; *(bf16x8*)(p1 + 8) = z8;
        float4 wv = *(const float4*)&p.w2raw[t * 4];
        f16x4 wo; wo[0] = (f16_t)wv.x; wo[1] = (f16_t)wv.y; wo[2] = (f16_t)wv.z; wo[3] = (f16_t)wv.w;
        *(f16x4*)&p.w2f[t * 4] = wo;
    }
}

// ---------------------------------------------------------------------------
// Phase A unit (u in [0,1792)): conv1 (512) | tp gemm (256) | ap gemm (1024)
// ---------------------------------------------------------------------------
__device__ void phaseA_unit(int u, int tid, float* smem,
                            float* sred, float* sredq, const KP& p)
{
    const int w = tid >> 6, l = tid & 63;
    const int lm = l & 15, lh = l >> 4, lk = lh * 8;
    if (u < 512) {
        const int bx = u >> 6, by = u & 63;
        const int bt0 = bx * 32, m0 = by * 16;
        const int b = bt0 >> 7, tbase = bt0 & 127;
        f32x4 acc0 = (f32x4)(0.0f), acc1 = (f32x4)(0.0f);
        conv_wave_partial(p.wc1, p.xp0, m0, b, tbase, w, l, acc0, acc1);
        float* sl = smem + w * 528;
        #pragma unroll
        for (int r = 0; r < 4; ++r) {
            sl[(lh * 4 + r) * 33 + lm] = acc0[r];
            sl[(lh * 4 + r) * 33 + 16 + lm] = acc1[r];
        }
        __syncthreads();
        const int mm = tid >> 5, nn = tid & 31;
        float v = 0.f;
        #pragma unroll
        for (int ww = 0; ww < 8; ++ww) v += smem[ww * 528 + mm * 33 + nn];
        v = fmaxf(v + p.db1[m0 + mm], 0.f);
        float s = wave_red_add(v), q = wave_red_add(v * v);
        if (l == 0) { sred[w] = s; sredq[w] = q; }
        p.xp1[(size_t)(b * 130 + 1 + tbase + nn) * 1024 + m0 + mm] = (bf16_t)v;
        __syncthreads();
        if (tid == 0) {
            float ts = 0.f, tq = 0.f;
            #pragma unroll
            for (int ww = 0; ww < 8; ++ww) { ts += sred[ww]; tq += sredq[ww]; }
            p.bstat1[u * 2] = ts; p.bstat1[u * 2 + 1] = tq;
        }
    } else {
        const int is_tp = (u < 768) ? 1 : 0;
        int d0, r0;
        const bf16_t *At, *Bm;
        if (is_tp) {
            const int un = u - 512;
            d0 = (un & 31) * 32; r0 = (un >> 5) * 32;
            At = p.topT; Bm = p.text_bf;
        } else {
            const int un = u - 768;
            d0 = (un & 31) * 32; r0 = (un >> 5) * 32;
            At = p.botT; Bm = p.audio_bf;
        }
        const int koff = w * 128;
        const bf16_t* Ap = At + (size_t)(d0 + lm) * 1024 + koff + lk;
        const bf16_t* Bp = Bm + (size_t)(r0 + lm) * 1024 + koff + lk;
        bf16x8 qa0[4], qa1[4], qb0[4], qb1[4];
        #pragma unroll
        for (int cc = 0; cc < 4; ++cc) {
            qa0[cc] = *(const bf16x8*)(Ap + cc * 32);
            qa1[cc] = *(const bf16x8*)(Ap + 16384 + cc * 32);
            qb0[cc] = *(const bf16x8*)(Bp + cc * 32);
            qb1[cc] = *(const bf16x8*)(Bp + 16384 + cc * 32);
        }
        f32x4 acc[2][2];
        #pragma unroll
        for (int mt = 0; mt < 2; ++mt)
            #pragma unroll
            for (int nt = 0; nt < 2; ++nt) acc[mt][nt] = (f32x4)(0.0f);
        #pragma unroll
        for (int cc = 0; cc < 4; ++cc) {
            acc[0][0] = __builtin_amdgcn_mfma_f32_16x16x32_bf16(qa0[cc], qb0[cc], acc[0][0], 0, 0, 0);
            acc[0][1] = __builtin_amdgcn_mfma_f32_16x16x32_bf16(qa0[cc], qb1[cc], acc[0][1], 0, 0, 0);
            acc[1][0] = __builtin_amdgcn_mfma_f32_16x16x32_bf16(qa1[cc], qb0[cc], acc[1][0], 0, 0, 0);
            acc[1][1] = __builtin_amdgcn_mfma_f32_16x16x32_bf16(qa1[cc], qb1[cc], acc[1][1], 0, 0, 0);
        }
        float* sl = smem + w * 1056;
        #pragma unroll
        for (int mt = 0; mt < 2; ++mt)
            #pragma unroll
            for (int nt = 0; nt < 2; ++nt)
                #pragma unroll
                for (int r = 0; r < 4; ++r)
                    sl[(mt * 16 + lh * 4 + r) * 33 + nt * 16 + lm] = acc[mt][nt][r];
        __syncthreads();
        const int m = tid >> 4, n2 = (tid & 15) * 2;
        float v0 = 0.f, v1 = 0.f;
        #pragma unroll
        for (int ww = 0; ww < 8; ++ww) {
            v0 += smem[ww * 1056 + m * 33 + n2];
            v1 += smem[ww * 1056 + m * 33 + n2 + 1];
        }
        if (is_tp) {
            const float bb = p.ab1[d0 + m];
            p.tp[(size_t)(r0 + n2) * 1024 + d0 + m] = (f16_t)(v0 + bb);
            p.tp[(size_t)(r0 + n2 + 1) * 1024 + d0 + m] = (f16_t)(v1 + bb);
        } else {
            const int h = d0 + m, hq = h >> 2, hr = h & 3;
            const int a0 = r0 + n2;
            const int bbk = a0 >> 9, al = a0 & 511;
            p.apT4[((size_t)hq * 1024 + bbk * 512 + al) * 4 + hr] = (f16_t)v0;
            p.apT4[((size_t)hq * 1024 + bbk * 512 + al + 1) * 4 + hr] = (f16_t)v1;
        }
    }
}

// ---------------------------------------------------------------------------
// Phase B unit (u in [0,768)): conv2 GN1-folded (512) | logits (256)
// ---------------------------------------------------------------------------
__device__ void phaseB_unit(int u, int tid, float* smem,
                            float* sred, float* sredq, float* sr8, float* sq8,
                            const KP& p)
{
    if (u < 512) {
        const int w = tid >> 6, l = tid & 63;
        const int lm = l & 15, lh = l >> 4;
        const int bx = u >> 6, by = u & 63;
        const int bt0 = bx * 32, m0 = by * 16;
        const int b = bt0 >> 7, tbase = bt0 & 127;
        f32x4 acc0 = (f32x4)(0.0f), acc1 = (f32x4)(0.0f);
        conv_wave_partial(p.wc2, p.xp1, m0, b, tbase, w, l, acc0, acc1);
        float* sl = smem + w * 528;
        #pragma unroll
        for (int r = 0; r < 4; ++r) {
            sl[(lh * 4 + r) * 33 + lm] = acc0[r];
            sl[(lh * 4 + r) * 33 + 16 + lm] = acc1[r];
        }
        __syncthreads();
        const int mm = tid >> 5, nn = tid & 31;
        float vraw = 0.f;
        #pragma unroll
        for (int ww = 0; ww < 8; ++ww) vraw += smem[ww * 528 + mm * 33 + nn];
        float mu, rsig;
        reduce_bstat(p.bstat1, b, tid, sr8, sq8, mu, rsig);
        const int o = m0 + mm, tloc = tbase + nn;
        float sg = p.SgF[o], sb = p.SbF[o];
        if (tloc == 0)   { sg -= p.Sg3[o * 3];     sb -= p.Sb3[o * 3]; }
        if (tloc == 127) { sg -= p.Sg3[o * 3 + 2]; sb -= p.Sb3[o * 3 + 2]; }
        float v = fmaxf(rsig * vraw + sb - mu * rsig * sg + p.db2[o], 0.f);
        float s = wave_red_add(v), q = wave_red_add(v * v);
        if ((tid & 63) == 0) { sred[tid >> 6] = s; sredq[tid >> 6] = q; }
        p.y2[(size_t)(b * 128 + tloc) * 1024 + o] = (bf16_t)v;
        __syncthreads();
        if (tid == 0) {
            float ts = 0.f, tq = 0.f;
            #pragma unroll
            for (int ww = 0; ww < 8; ++ww) { ts += sred[ww]; tq += sredq[ww]; }
            p.bstat2[u * 2] = ts; p.bstat2[u * 2 + 1] = tq;
        }
    } else {
        const int lb = u - 512;
        const int hc = lb >> 6, btp = lb & 63;
        const int bt0 = btp * 4;
        const int b = bt0 >> 7;
        const int a = tid;
        const f16_t* tpr = p.tp + (size_t)bt0 * 1024 + hc * 256;
        const f16_t* w2r = p.w2f + hc * 256;
        const f16_t* apc = p.apT4 + ((size_t)(hc * 64) * 1024 + b * 512 + a) * 4;
        float acc[4] = {0.f, 0.f, 0.f, 0.f};
        const f16x2 zero = (f16x2)(f16_t)0.0f;
#define L_A0(i) (*(const f16x4*)(apc + (size_t)(2 * (i)) * 4096))
#define L_A1(i) (*(const f16x4*)(apc + (size_t)(2 * (i) + 1) * 4096))
        constexpr int PF = 4;
        f16x4 pa[PF], pb[PF];
        #pragma unroll
        for (int i = 0; i < PF; ++i) { pa[i] = L_A0(i); pb[i] = L_A1(i); }
        #pragma unroll
        for (int i = 0; i < 32; ++i) {
            const int sl = i % PF;
            const int hq = 2 * i;
            f16x4 a0 = pa[sl], a1 = pb[sl];
            f16x4 w0 = *(const f16x4*)&w2r[hq * 4];
            f16x4 w1 = *(const f16x4*)&w2r[hq * 4 + 4];
            #pragma unroll
            for (int r = 0; r < 4; ++r) {
                f16x4 t0 = *(const f16x4*)&tpr[r * 1024 + hq * 4];
                f16x4 t1 = *(const f16x4*)&tpr[r * 1024 + hq * 4 + 4];
                f16x2 pp;
                pp = __builtin_elementwise_max((f16x2){t0[0] + a0[0], t0[1] + a0[1]}, zero);
                acc[r] = dot2_acc(pp, (f16x2){w0[0], w0[1]}, acc[r]);
                pp = __builtin_elementwise_max((f16x2){t0[2] + a0[2], t0[3] + a0[3]}, zero);
                acc[r] = dot2_acc(pp, (f16x2){w0[2], w0[3]}, acc[r]);
                pp = __builtin_elementwise_max((f16x2){t1[0] + a1[0], t1[1] + a1[1]}, zero);
                acc[r] = dot2_acc(pp, (f16x2){w1[0], w1[1]}, acc[r]);
                pp = __builtin_elementwise_max((f16x2){t1[2] + a1[2], t1[3] + a1[3]}, zero);
                acc[r] = dot2_acc(pp, (f16x2){w1[2], w1[3]}, acc[r]);
            }
            const int nx = i + PF;
            if (nx < 32) { pa[sl] = L_A0(nx); pb[sl] = L_A1(nx); }
        }
#undef L_A0
#undef L_A1
        float* dst = p.lp + (size_t)(hc * 256 + bt0) * 512 + a;
        #pragma unroll
        for (int r = 0; r < 4; ++r) dst[(size_t)r * 512] = acc[r];
    }
}

// ---------------------------------------------------------------------------
// Phase C unit (u in [0,288)): softmax combine (256) | conv3+GN2 (32)
// ---------------------------------------------------------------------------
__device__ void phaseC_unit(int u, int tid,
                            float* sred, float* sredq, float* sr8, float* sq8,
                            const KP& p)
{
    if (u < 256) {
        const int bt = u, t = bt & 127;
        const int a = tid;
        const int lane = a & 63, wid = a >> 6;
        const size_t base = (size_t)bt * 512 + a;
        float v = p.lp[base] + p.lp[131072 + base] + p.lp[262144 + base] + p.lp[393216 + base];
        v += p.ab2[0] - 0.1f * fabsf((float)a - 4.0f * (float)t);
        float m = v;
        #pragma unroll
        for (int off = 32; off > 0; off >>= 1) m = fmaxf(m, __shfl_xor(m, off));
        if (lane == 0) sred[wid] = m;
        __syncthreads();
        float M = sred[0];
        #pragma unroll
        for (int i = 1; i < 8; ++i) M = fmaxf(M, sred[i]);
        const float e = expf(v - M);
        float s = e;
        #pragma unroll
        for (int off = 32; off > 0; off >>= 1) s += __shfl_xor(s, off);
        if (lane == 0) sredq[wid] = s;
        __syncthreads();
        float S = sredq[0];
        #pragma unroll
        for (int i = 1; i < 8; ++i) S += sredq[i];
        p.out[(size_t)bt * 512 + a] = e * (1.0f / S);
    } else {
        const int cb = u - 256;
        const int b = (cb * 8) >> 7;
        float mu, rsig;
        reduce_bstat(p.bstat2, b, tid, sr8, sq8, mu, rsig);
        const int lane = tid & 63, ww = tid >> 6;
        const int bt = cb * 8 + ww;
        const bf16_t* row = p.y2 + (size_t)bt * 1024 + lane * 16;
        float s1 = 0.f, s2 = 0.f, s3 = 0.f;
        #pragma unroll
        for (int c = 0; c < 2; ++c) {
            bf16x8 yv = *(const bf16x8*)(row + c * 8);
            #pragma unroll
            for (int j = 0; j < 8; ++j) {
                const int i = lane * 16 + c * 8 + j;
                const float gw = p.g2[i] * p.w3[i];
                s1 += gw * (float)yv[j];
                s2 += gw;
                s3 += p.bet2[i] * p.w3[i];
            }
        }
        #pragma unroll
        for (int off = 32; off > 0; off >>= 1) {
            s1 += __shfl_xor(s1, off);
            s2 += __shfl_xor(s2, off);
            s3 += __shfl_xor(s3, off);
        }
        if (lane == 0) {
            const float t = rsig * (s1 - mu * s2) + s3 + p.b3[0];
            p.out[131072 + bt] = fmaxf(t, 0.f) + log1pf(expf(-fabsf(t)));
        }
    }
}

// ---------------------------------------------------------------------------
// cooperative mega-kernel (256 blocks x 512 threads, grid-stride phases)
// ---------------------------------------------------------------------------
__global__ __launch_bounds__(512, 2) void fused_k(KP p)
{
    cg::grid_group gg = cg::this_grid();
    __shared__ float smem[8448];
    __shared__ float sred[8], sredq[8], sr8[8], sq8[8];
    const int gs = gridDim.x;
    const int bid = blockIdx.x;
    const int tid = threadIdx.x;

    {   // Phase P: prep, 2689 unit-pairs
        const int half = tid >> 8, t = tid & 255;
        float* tile = smem + half * 1056;
        for (int i = bid; i < 2689; i += gs) {
            __syncthreads();
            const int u = i * 2 + half;
            if (u < 5377) prep_unit(u, t, tile, p);
        }
    }
    gg.sync();
    for (int u = bid; u < 1792; u += gs) { __syncthreads(); phaseA_unit(u, tid, smem, sred, sredq, p); }
    gg.sync();
    for (int u = bid; u < 768; u += gs) { __syncthreads(); phaseB_unit(u, tid, smem, sred, sredq, sr8, sq8, p); }
    gg.sync();
    for (int u = bid; u < 288; u += gs) { __syncthreads(); phaseC_unit(u, tid, sred, sredq, sr8, sq8, p); }
}

// ---------------------------------------------------------------------------
// fallback separate kernels (exact R16 structure via the same unit functions)
// ---------------------------------------------------------------------------
__global__ __launch_bounds__(256) void prep_sep(KP p) {
    __shared__ float tile[1056];
    prep_unit(blockIdx.x, threadIdx.x, tile, p);
}
__global__ __launch_bounds__(512) void pA_sep(KP p) {
    __shared__ float smem[8448];
    __shared__ float sred[8], sredq[8];
    phaseA_unit(blockIdx.x, threadIdx.x, smem, sred, sredq, p);
}
__global__ __launch_bounds__(512) void pB_sep(KP p) {
    __shared__ float smem[8448];
    __shared__ float sred[8], sredq[8], sr8[8], sq8[8];
    phaseB_unit(blockIdx.x, threadIdx.x, smem, sred, sredq, sr8, sq8, p);
}
__global__ __launch_bounds__(512) void pC_sep(KP p) {
    __shared__ float sred[8], sredq[8], sr8[8], sq8[8];
    phaseC_unit(blockIdx.x, threadIdx.x, sred, sredq, sr8, sq8, p);
}

extern "C" void kernel_launch(void* const* d_in, const int* in_sizes, int n_in,
                              void* d_out, int out_size, void* d_ws, size_t ws_size,
                              hipStream_t stream) {
    char* ws = (char*)d_ws;

    KP kp;
    kp.text   = (const float*)d_in[0];
    kp.audio  = (const float*)d_in[1];
    kp.w1     = (const float*)d_in[2];
    kp.ab1    = (const float*)d_in[3];
    kp.w2raw  = (const float*)d_in[4];
    kp.ab2    = (const float*)d_in[5];
    kp.w1c    = (const float*)d_in[6];
    kp.db1    = (const float*)d_in[7];
    kp.g1     = (const float*)d_in[8];
    kp.b1g    = (const float*)d_in[9];
    kp.w2c    = (const float*)d_in[10];
    kp.db2    = (const float*)d_in[11];
    kp.g2     = (const float*)d_in[12];
    kp.bet2   = (const float*)d_in[13];
    kp.w3     = (const float*)d_in[14];
    kp.b3     = (const float*)d_in[15];

    kp.text_bf  = (bf16_t*)(ws + OFF_TEXTBF);
    kp.audio_bf = (bf16_t*)(ws + OFF_AUDIOBF);
    kp.topT     = (bf16_t*)(ws + OFF_W1TOP);
    kp.botT     = (bf16_t*)(ws + OFF_W1BOT);
    kp.wc1      = (bf16_t*)(ws + OFF_WC1);
    kp.wc2      = (bf16_t*)(ws + OFF_WC2);
    kp.tp       = (f16_t*) (ws + OFF_TP);
    kp.w2f      = (f16_t*) (ws + OFF_W2F);
    kp.apT4     = (f16_t*) (ws + OFF_APT);
    kp.xp0      = (bf16_t*)(ws + OFF_XP0);
    kp.xp1      = (bf16_t*)(ws + OFF_XP1);
    kp.y2       = (bf16_t*)(ws + OFF_Y2);
    kp.bstat1   = (float*) (ws + OFF_BST1);
    kp.bstat2   = (float*) (ws + OFF_BST2);
    kp.lp       = (float*) (ws + OFF_LP);
    kp.Sg3      = (float*) (ws + OFF_SG);
    kp.Sb3      = (float*) (ws + OFF_SB);
    kp.SgF      = (float*) (ws + OFF_SGF);
    kp.SbF      = (float*) (ws + OFF_SBF);
    kp.out      = (float*)d_out;

    void* args[] = { (void*)&kp };
    hipError_t err = hipLaunchCooperativeKernel((void*)fused_k, dim3(256),
                                                dim3(512), args, 0, stream);
    if (err != hipSuccess) {
        (void)hipGetLastError();   // clear sticky error, use proven 4-kernel path
        prep_sep<<<dim3(5377), 256, 0, stream>>>(kp);
        pA_sep<<<dim3(1792), 512, 0, stream>>>(kp);
        pB_sep<<<dim3(768), 512, 0, stream>>>(kp);
        pC_sep<<<dim3(288), 512, 0, stream>>>(kp);
    }
}

// Round 8
// 190.892 us; speedup vs baseline: 1.5443x; 1.5443x over previous
//
#include <hip/hip_runtime.h>
#include <hip/hip_bf16.h>

// ---------------------------------------------------------------------------
// MonotonicAlignmentSearch R20: R16 structure (best proven, 179.5us) with
// compiler-proof load pipelining. R14-R19 counters showed every phase ~94%
// stalled (MfmaUtil 1-3%, VALUBusy 2-6%) because hipcc sinks builtin loads
// next to their uses (VGPR 40-56 => ~1 load in flight/wave). Fix: inline-asm
// global_load_dwordx4 batches (36/wave conv, 16/wave gemm) + counted
// s_waitcnt vmcnt(N) + sched_barrier(0) (rule #18). asm volatile is program-
// ordered and pins results in VGPRs => real MLP. Everything else verbatim R16.
// B=2, TT=128, TA=512, H=1024.
// ---------------------------------------------------------------------------

typedef __bf16 bf16_t;
typedef __bf16 bf16x8 __attribute__((ext_vector_type(8)));
typedef __bf16 bf16x4 __attribute__((ext_vector_type(4)));
typedef float  f32x4  __attribute__((ext_vector_type(4)));
typedef _Float16 f16_t;
typedef _Float16 f16x2 __attribute__((ext_vector_type(2)));
typedef _Float16 f16x4 __attribute__((ext_vector_type(4)));
typedef int v4i __attribute__((ext_vector_type(4)));

#define EPSV 1e-5f

// batched load: result pinned in VGPRs, issue order = program order
#define GLD(dst, ptr, off) \
    asm volatile("global_load_dwordx4 %0, %1, off offset:%c2" \
                 : "=v"(dst) : "v"(ptr), "n"(off) : "memory")
// counted wait + scheduling fence (rule #18: MFMA can hoist past bare asm)
#define WAITV(n) do { \
    asm volatile("s_waitcnt vmcnt(%c0)" :: "n"(n) : "memory"); \
    __builtin_amdgcn_sched_barrier(0); } while (0)

__device__ __forceinline__ bf16x8 as_bf16x8(v4i v) {
    union { v4i i; bf16x8 h; } u; u.i = v; return u.h;
}

// ---- workspace offsets (bytes) — no overlays, ~26.3 MB << 256 MB ws -------
#define OFF_TEXTBF   0u
#define OFF_AUDIOBF  524288u
#define OFF_W1TOP    2621440u
#define OFF_W1BOT    4718592u
#define OFF_WC1      6815744u
#define OFF_WC2      13107200u
#define OFF_TP       19398656u
#define OFF_W2F      19922944u
#define OFF_APT      20447232u
#define OFF_XP0      22544384u
#define OFF_XP1      23076864u
#define OFF_Y2       23609344u
#define OFF_BST1     24133632u
#define OFF_BST2     24137728u
#define OFF_LP       24141824u
#define OFF_SG       26238976u
#define OFF_SB       26251264u
#define OFF_SGF      26263552u
#define OFF_SBF      26267648u

// ---------------------------------------------------------------------------
// prep: [0,1280) cvt activations; [1280,3328) w1 transpose-cast;
// [3328,5376) conv-weight cvt (wc2 g-scaled + Sg/Sb/SgF/SbF sums);
// 5376: zero pads + w2->f16.   (verbatim R16)
// ---------------------------------------------------------------------------
__global__ __launch_bounds__(256) void prep_k(
    const float* __restrict__ text, const float* __restrict__ audio,
    const float* __restrict__ w1,
    const float* __restrict__ w1c, const float* __restrict__ w2c,
    const float* __restrict__ w2,
    const float* __restrict__ g1, const float* __restrict__ b1g,
    bf16_t* __restrict__ text_bf, bf16_t* __restrict__ xp0,
    bf16_t* __restrict__ audio_bf,
    bf16_t* __restrict__ topT, bf16_t* __restrict__ botT,
    bf16_t* __restrict__ wc1, bf16_t* __restrict__ wc2,
    bf16_t* __restrict__ xp1, f16_t* __restrict__ w2f,
    float* __restrict__ Sg, float* __restrict__ Sb,
    float* __restrict__ SgF, float* __restrict__ SbF)
{
    __shared__ float tile[32][33];
    const int bid = blockIdx.x;
    if (bid < 1280) {
        const int e = (bid * 256 + threadIdx.x) * 4;   // 1310720 total
        if (e < 262144) {
            float4 v = *(const float4*)&text[e];
            bf16x4 o; o[0] = (bf16_t)v.x; o[1] = (bf16_t)v.y; o[2] = (bf16_t)v.z; o[3] = (bf16_t)v.w;
            *(bf16x4*)&text_bf[e] = o;
            const int bt = e >> 10, h = e & 1023;
            const int b = bt >> 7, t = bt & 127;
            *(bf16x4*)&xp0[(size_t)(b * 130 + 1 + t) * 1024 + h] = o;
        } else {
            const int ea = e - 262144;
            float4 v = *(const float4*)&audio[ea];
            bf16x4 o; o[0] = (bf16_t)v.x; o[1] = (bf16_t)v.y; o[2] = (bf16_t)v.z; o[3] = (bf16_t)v.w;
            *(bf16x4*)&audio_bf[ea] = o;
        }
    } else if (bid < 3328) {
        const int b2 = bid - 1280;
        const int bx = b2 & 31, by = b2 >> 5;          // (32, 64)
        const int tx = threadIdx.x & 31, ty = threadIdx.x >> 5;
        #pragma unroll
        for (int j = 0; j < 4; ++j)
            tile[ty + j * 8][tx] = w1[(size_t)(by * 32 + ty + j * 8) * 1024 + bx * 32 + tx];
        __syncthreads();
        bf16_t* out = (by < 32) ? topT : botT;
        const int hbase = (by & 31) * 32;
        #pragma unroll
        for (int j = 0; j < 4; ++j) {
            const int d = bx * 32 + ty + j * 8;
            out[(size_t)d * 1024 + hbase + tx] = (bf16_t)tile[tx][ty + j * 8];
        }
    } else if (bid < 5376) {
        int b2 = bid - 3328;
        const int is2 = (b2 >= 1024) ? 1 : 0;
        const float* w = is2 ? w2c : w1c;
        bf16_t* wc = is2 ? wc2 : wc1;
        b2 &= 1023;
        const int o = b2, i4 = threadIdx.x;            // one block per out-chan
        const float* src = w + (size_t)o * 3072 + i4 * 12;
        float4 v0 = *(const float4*)&src[0];
        float4 v1 = *(const float4*)&src[4];
        float4 v2 = *(const float4*)&src[8];
        const float f[12] = {v0.x, v0.y, v0.z, v0.w, v1.x, v1.y, v1.z, v1.w, v2.x, v2.y, v2.z, v2.w};
        float g4[4] = {1.f, 1.f, 1.f, 1.f}, bb4[4] = {0.f, 0.f, 0.f, 0.f};
        if (is2) {
            float4 gv = *(const float4*)&g1[i4 * 4];
            float4 bv = *(const float4*)&b1g[i4 * 4];
            g4[0] = gv.x; g4[1] = gv.y; g4[2] = gv.z; g4[3] = gv.w;
            bb4[0] = bv.x; bb4[1] = bv.y; bb4[2] = bv.z; bb4[3] = bv.w;
        }
        float sgr[3] = {0.f, 0.f, 0.f}, sbr[3] = {0.f, 0.f, 0.f};
        #pragma unroll
        for (int r = 0; r < 3; ++r) {
            bf16x4 o4;
            #pragma unroll
            for (int j = 0; j < 4; ++j) {
                const float wv = f[j * 3 + r];
                const float ws = wv * g4[j];
                sgr[r] += ws;
                sbr[r] += wv * bb4[j];
                o4[j] = (bf16_t)(is2 ? ws : wv);
            }
            *(bf16x4*)&wc[(size_t)r * 1048576 + (size_t)o * 1024 + i4 * 4] = o4;
        }
        if (is2) {
            #pragma unroll
            for (int off = 32; off > 0; off >>= 1) {
                #pragma unroll
                for (int r = 0; r < 3; ++r) {
                    sgr[r] += __shfl_xor(sgr[r], off);
                    sbr[r] += __shfl_xor(sbr[r], off);
                }
            }
            float* red = &tile[0][0];
            const int wid = threadIdx.x >> 6, lane = threadIdx.x & 63;
            if (lane == 0) {
                #pragma unroll
                for (int r = 0; r < 3; ++r) {
                    red[wid * 6 + r] = sgr[r];
                    red[wid * 6 + 3 + r] = sbr[r];
                }
            }
            __syncthreads();
            if (threadIdx.x < 6) {
                const float v = red[threadIdx.x] + red[6 + threadIdx.x]
                              + red[12 + threadIdx.x] + red[18 + threadIdx.x];
                if (threadIdx.x < 3) Sg[o * 3 + threadIdx.x] = v;
                else                 Sb[o * 3 + threadIdx.x - 3] = v;
                red[24 + threadIdx.x] = v;
            }
            __syncthreads();
            if (threadIdx.x == 0)      SgF[o] = red[24] + red[25] + red[26];
            else if (threadIdx.x == 1) SbF[o] = red[27] + red[28] + red[29];
        }
    } else {
        const int tid = threadIdx.x;
        const int rowmap[4] = {0, 129, 130, 259};
        const int f = tid * 16;
        const int r = f >> 10, w = f & 1023;
        bf16x8 z8 = (bf16x8)(bf16_t)0.0f;
        bf16_t* p0 = xp0 + (size_t)rowmap[r] * 1024 + w;
        bf16_t* p1 = xp1 + (size_t)rowmap[r] * 1024 + w;
        *(bf16x8*)p0 = z8; *(bf16x8*)(p0 + 8) = z8;
        *(bf16x8*)p1 = z8; *(bf16x8*)(p1 + 8) = z8;
        float4 wv = *(const float4*)&w2[tid * 4];
        f16x4 wo; wo[0] = (f16_t)wv.x; wo[1] = (f16_t)wv.y; wo[2] = (f16_t)wv.z; wo[3] = (f16_t)wv.w;
        *(f16x4*)&w2f[tid * 4] = wo;
    }
}

// ---------------------------------------------------------------------------
// helpers
// ---------------------------------------------------------------------------
__device__ __forceinline__ float wave_red_add(float v) {
    #pragma unroll
    for (int off = 32; off > 0; off >>= 1) v += __shfl_xor(v, off);
    return v;
}

// Per-wave conv K-slice: wave w handles k in [w*128,+128) of each tap.
// 36 asm-batched loads (all in flight), consumed in retirement order with
// counted vmcnt. Bases: 3 A taps; B centered at tap1 (offsets +-2048 fit
// the 13-bit signed immediate).
__device__ __forceinline__ void conv_wave_partial(
    const bf16_t* __restrict__ Wc, const bf16_t* __restrict__ xp,
    int m0, int b, int tbase, int w, int l, f32x4& acc0, f32x4& acc1)
{
    const int lm = l & 15, lk = (l >> 4) * 8;
    const int koff = w * 128;
    const bf16_t* aq0 = Wc + (size_t)(m0 + lm) * 1024 + koff + lk;
    const bf16_t* aq1 = aq0 + 1048576;
    const bf16_t* aq2 = aq0 + 2097152;
    const bf16_t* bqc = xp + (size_t)(b * 130 + tbase + lm) * 1024 + koff + lk + 1024; // tap-1 center
    const bf16_t* bqd = bqc + 16384;
    v4i A[12], B0[12], B1[12];
    // chunk c: tap rr=c>>2, cc=c&3. A imm = cc*64; B imm = (rr-1)*2048+cc*64.
    GLD(A[0],  aq0,   0); GLD(B0[0],  bqc, -2048); GLD(B1[0],  bqd, -2048);
    GLD(A[1],  aq0,  64); GLD(B0[1],  bqc, -1984); GLD(B1[1],  bqd, -1984);
    GLD(A[2],  aq0, 128); GLD(B0[2],  bqc, -1920); GLD(B1[2],  bqd, -1920);
    GLD(A[3],  aq0, 192); GLD(B0[3],  bqc, -1856); GLD(B1[3],  bqd, -1856);
    GLD(A[4],  aq1,   0); GLD(B0[4],  bqc,     0); GLD(B1[4],  bqd,     0);
    GLD(A[5],  aq1,  64); GLD(B0[5],  bqc,    64); GLD(B1[5],  bqd,    64);
    GLD(A[6],  aq1, 128); GLD(B0[6],  bqc,   128); GLD(B1[6],  bqd,   128);
    GLD(A[7],  aq1, 192); GLD(B0[7],  bqc,   192); GLD(B1[7],  bqd,   192);
    GLD(A[8],  aq2,   0); GLD(B0[8],  bqc,  2048); GLD(B1[8],  bqd,  2048);
    GLD(A[9],  aq2,  64); GLD(B0[9],  bqc,  2112); GLD(B1[9],  bqd,  2112);
    GLD(A[10], aq2, 128); GLD(B0[10], bqc,  2176); GLD(B1[10], bqd,  2176);
    GLD(A[11], aq2, 192); GLD(B0[11], bqc,  2240); GLD(B1[11], bqd,  2240);
#define CMF(c, n) \
    WAITV(n); \
    acc0 = __builtin_amdgcn_mfma_f32_16x16x32_bf16(as_bf16x8(A[c]), as_bf16x8(B0[c]), acc0, 0, 0, 0); \
    acc1 = __builtin_amdgcn_mfma_f32_16x16x32_bf16(as_bf16x8(A[c]), as_bf16x8(B1[c]), acc1, 0, 0, 0)
    CMF(0, 33); CMF(1, 30); CMF(2, 27); CMF(3, 24); CMF(4, 21); CMF(5, 18);
    CMF(6, 15); CMF(7, 12); CMF(8,  9); CMF(9,  6); CMF(10, 3); CMF(11, 0);
#undef CMF
}

// ---------------------------------------------------------------------------
// P2: blocks [0,512) conv1 tiles (16ch x 32bt, 8-way K-split, LDS reduce);
//     [512,768) tp gemm; [768,1792) ap gemm (32x32, 8-way K-split).
// Gemm loads asm-batched (16 in flight).
// ---------------------------------------------------------------------------
__global__ __launch_bounds__(512) void p2_k(
    const bf16_t* __restrict__ wc1, const bf16_t* __restrict__ xp0,
    const float* __restrict__ d_b1, bf16_t* __restrict__ xp1,
    float* __restrict__ bstat1,
    const bf16_t* __restrict__ text_bf, const bf16_t* __restrict__ w1topT,
    const float* __restrict__ a_b1, f16_t* __restrict__ tp,
    const bf16_t* __restrict__ audio_bf, const bf16_t* __restrict__ w1botT,
    f16_t* __restrict__ apT4)
{
    __shared__ float smem[8448];                 // gemm: [8][32][33]; conv: [8][16][33]
    __shared__ float sred[8], sredq[8];
    const int bid = blockIdx.x;
    const int tid = threadIdx.x;
    const int w = tid >> 6, l = tid & 63;
    const int lm = l & 15, lh = l >> 4, lk = lh * 8;
    if (bid < 512) {
        // ---- conv1 tile: bx = bid>>6 (bt group), by = bid&63 (chan group) --
        const int bx = bid >> 6, by = bid & 63;
        const int bt0 = bx * 32, m0 = by * 16;
        const int b = bt0 >> 7, tbase = bt0 & 127;
        f32x4 acc0 = (f32x4)(0.0f), acc1 = (f32x4)(0.0f);
        conv_wave_partial(wc1, xp0, m0, b, tbase, w, l, acc0, acc1);
        float* sl = smem + w * 528;
        #pragma unroll
        for (int r = 0; r < 4; ++r) {
            sl[(lh * 4 + r) * 33 + lm] = acc0[r];
            sl[(lh * 4 + r) * 33 + 16 + lm] = acc1[r];
        }
        __syncthreads();
        const int mm = tid >> 5, nn = tid & 31;  // chan-local, bt-local
        float v = 0.f;
        #pragma unroll
        for (int ww = 0; ww < 8; ++ww) v += smem[ww * 528 + mm * 33 + nn];
        v = fmaxf(v + d_b1[m0 + mm], 0.f);
        float s = wave_red_add(v), q = wave_red_add(v * v);
        if (l == 0) { sred[w] = s; sredq[w] = q; }
        xp1[(size_t)(b * 130 + 1 + tbase + nn) * 1024 + m0 + mm] = (bf16_t)v;
        __syncthreads();
        if (tid == 0) {
            float ts = 0.f, tq = 0.f;
            #pragma unroll
            for (int ww = 0; ww < 8; ++ww) { ts += sred[ww]; tq += sredq[ww]; }
            bstat1[bid * 2] = ts; bstat1[bid * 2 + 1] = tq;
        }
    } else {
        // ---- gemm 32x32 tile, 8-way K-split (wave w: k in [w*128,+128)) ---
        const bf16_t *At, *Bm;
        int d0, r0, is_tp;
        if (bid < 768) {
            const int unit = bid - 512;          // 256 units: 8 bt x 32 d
            d0 = (unit & 31) * 32; r0 = (unit >> 5) * 32;
            At = w1topT; Bm = text_bf; is_tp = 1;
        } else {
            const int unit = bid - 768;          // 1024 units: 32 a x 32 d
            d0 = (unit & 31) * 32; r0 = (unit >> 5) * 32;
            At = w1botT; Bm = audio_bf; is_tp = 0;
        }
        const int koff = w * 128;
        const bf16_t* Ap0 = At + (size_t)(d0 + lm) * 1024 + koff + lk;
        const bf16_t* Ap1 = Ap0 + 16384;
        const bf16_t* Bp0 = Bm + (size_t)(r0 + lm) * 1024 + koff + lk;
        const bf16_t* Bp1 = Bp0 + 16384;
        v4i qa0[4], qa1[4], qb0[4], qb1[4];
        GLD(qa0[0], Ap0,   0); GLD(qa1[0], Ap1,   0); GLD(qb0[0], Bp0,   0); GLD(qb1[0], Bp1,   0);
        GLD(qa0[1], Ap0,  64); GLD(qa1[1], Ap1,  64); GLD(qb0[1], Bp0,  64); GLD(qb1[1], Bp1,  64);
        GLD(qa0[2], Ap0, 128); GLD(qa1[2], Ap1, 128); GLD(qb0[2], Bp0, 128); GLD(qb1[2], Bp1, 128);
        GLD(qa0[3], Ap0, 192); GLD(qa1[3], Ap1, 192); GLD(qb0[3], Bp0, 192); GLD(qb1[3], Bp1, 192);
        f32x4 acc[2][2];
        #pragma unroll
        for (int mt = 0; mt < 2; ++mt)
            #pragma unroll
            for (int nt = 0; nt < 2; ++nt) acc[mt][nt] = (f32x4)(0.0f);
#define GMF(cc, n) \
        WAITV(n); \
        acc[0][0] = __builtin_amdgcn_mfma_f32_16x16x32_bf16(as_bf16x8(qa0[cc]), as_bf16x8(qb0[cc]), acc[0][0], 0, 0, 0); \
        acc[0][1] = __builtin_amdgcn_mfma_f32_16x16x32_bf16(as_bf16x8(qa0[cc]), as_bf16x8(qb1[cc]), acc[0][1], 0, 0, 0); \
        acc[1][0] = __builtin_amdgcn_mfma_f32_16x16x32_bf16(as_bf16x8(qa1[cc]), as_bf16x8(qb0[cc]), acc[1][0], 0, 0, 0); \
        acc[1][1] = __builtin_amdgcn_mfma_f32_16x16x32_bf16(as_bf16x8(qa1[cc]), as_bf16x8(qb1[cc]), acc[1][1], 0, 0, 0)
        GMF(0, 12); GMF(1, 8); GMF(2, 4); GMF(3, 0);
#undef GMF
        float* sl = smem + w * 1056;
        #pragma unroll
        for (int mt = 0; mt < 2; ++mt)
            #pragma unroll
            for (int nt = 0; nt < 2; ++nt)
                #pragma unroll
                for (int r = 0; r < 4; ++r)
                    sl[(mt * 16 + lh * 4 + r) * 33 + nt * 16 + lm] = acc[mt][nt][r];
        __syncthreads();
        const int m = tid >> 4, n2 = (tid & 15) * 2;     // d-local, row-local pair
        float v0 = 0.f, v1 = 0.f;
        #pragma unroll
        for (int ww = 0; ww < 8; ++ww) {
            v0 += smem[ww * 1056 + m * 33 + n2];
            v1 += smem[ww * 1056 + m * 33 + n2 + 1];
        }
        if (is_tp) {
            const float bb = a_b1[d0 + m];
            tp[(size_t)(r0 + n2) * 1024 + d0 + m] = (f16_t)(v0 + bb);
            tp[(size_t)(r0 + n2 + 1) * 1024 + d0 + m] = (f16_t)(v1 + bb);
        } else {
            const int h = d0 + m, hq = h >> 2, hr = h & 3;
            const int a0 = r0 + n2;
            const int bbk = a0 >> 9, al = a0 & 511;
            apT4[((size_t)hq * 1024 + bbk * 512 + al) * 4 + hr] = (f16_t)v0;
            apT4[((size_t)hq * 1024 + bbk * 512 + al + 1) * 4 + hr] = (f16_t)v1;
        }
    }
}

// reduce 256 (s,q) pairs for batch b from bstat (block-level, 512 threads).
__device__ __forceinline__ void reduce_bstat(
    const float* __restrict__ bstat, int b, int tid,
    float* sr, float* sq, float& mu, float& rsig)
{
    const int lane = tid & 63, wid = tid >> 6;
    float s = 0.f, q = 0.f;
    if (tid < 256) {
        float2 v = ((const float2*)bstat)[b * 256 + tid];
        s = v.x; q = v.y;
    }
    #pragma unroll
    for (int off = 32; off > 0; off >>= 1) {
        s += __shfl_xor(s, off);
        q += __shfl_xor(q, off);
    }
    if (lane == 0) { sr[wid] = s; sq[wid] = q; }
    __syncthreads();
    float ts = 0.f, tq = 0.f;
    #pragma unroll
    for (int i = 0; i < 8; ++i) { ts += sr[i]; tq += sq[i]; }
    const float cnt = 131072.f;
    mu = ts / cnt;
    const float var = tq / cnt - mu * mu;
    rsig = rsqrtf(var + EPSV);
}

// ---------------------------------------------------------------------------
// P3: blocks [0,512) conv2 tiles (GN1 folded analytically);
//     [512,768) logits blocks (512 threads = full a-range).
// ---------------------------------------------------------------------------
__device__ __forceinline__ float dot2_acc(f16x2 x, f16x2 w, float acc) {
#if __has_builtin(__builtin_amdgcn_fdot2)
    return __builtin_amdgcn_fdot2(x, w, acc, false);
#else
    return acc + (float)x[0] * (float)w[0] + (float)x[1] * (float)w[1];
#endif
}

__global__ __launch_bounds__(512) void p3_k(
    const bf16_t* __restrict__ wc2, const bf16_t* __restrict__ xp1,
    const float* __restrict__ d_b2, bf16_t* __restrict__ y2,
    float* __restrict__ bstat2, const float* __restrict__ bstat1,
    const float* __restrict__ SgF, const float* __restrict__ SbF,
    const float* __restrict__ Sg3, const float* __restrict__ Sb3,
    const f16_t* __restrict__ tp, const f16_t* __restrict__ apT4,
    const f16_t* __restrict__ w2f, float* __restrict__ lp)
{
    __shared__ float smem[4224];                 // conv: [8][16][33]
    __shared__ float sred[8], sredq[8], sr[8], sq[8];
    const int bid = blockIdx.x;
    const int tid = threadIdx.x;
    if (bid < 512) {
        const int w = tid >> 6, l = tid & 63;
        const int lm = l & 15, lh = l >> 4;
        const int bx = bid >> 6, by = bid & 63;
        const int bt0 = bx * 32, m0 = by * 16;
        const int b = bt0 >> 7, tbase = bt0 & 127;
        f32x4 acc0 = (f32x4)(0.0f), acc1 = (f32x4)(0.0f);
        conv_wave_partial(wc2, xp1, m0, b, tbase, w, l, acc0, acc1);
        float* sl = smem + w * 528;
        #pragma unroll
        for (int r = 0; r < 4; ++r) {
            sl[(lh * 4 + r) * 33 + lm] = acc0[r];
            sl[(lh * 4 + r) * 33 + 16 + lm] = acc1[r];
        }
        __syncthreads();
        const int mm = tid >> 5, nn = tid & 31;
        float vraw = 0.f;
        #pragma unroll
        for (int ww = 0; ww < 8; ++ww) vraw += smem[ww * 528 + mm * 33 + nn];
        float mu, rsig;
        reduce_bstat(bstat1, b, tid, sr, sq, mu, rsig);   // has its own barrier
        const int o = m0 + mm, tloc = tbase + nn;
        float sg = SgF[o], sb = SbF[o];
        if (tloc == 0)   { sg -= Sg3[o * 3];     sb -= Sb3[o * 3]; }
        if (tloc == 127) { sg -= Sg3[o * 3 + 2]; sb -= Sb3[o * 3 + 2]; }
        float v = fmaxf(rsig * vraw + sb - mu * rsig * sg + d_b2[o], 0.f);
        float s = wave_red_add(v), q = wave_red_add(v * v);
        if ((tid & 63) == 0) { sred[tid >> 6] = s; sredq[tid >> 6] = q; }
        y2[(size_t)(b * 128 + tloc) * 1024 + o] = (bf16_t)v;
        __syncthreads();
        if (tid == 0) {
            float ts = 0.f, tq = 0.f;
            #pragma unroll
            for (int ww = 0; ww < 8; ++ww) { ts += sred[ww]; tq += sredq[ww]; }
            bstat2[bid * 2] = ts; bstat2[bid * 2 + 1] = tq;
        }
    } else {
        const int lb = bid - 512;                       // 256 blocks
        const int hc = lb >> 6, btp = lb & 63;
        const int bt0 = btp * 4;
        const int b = bt0 >> 7;
        const int a = tid;                              // 0..511
        const f16_t* tpr = tp + (size_t)bt0 * 1024 + hc * 256;   // wave-uniform
        const f16_t* w2r = w2f + hc * 256;
        const f16_t* apc = apT4 + ((size_t)(hc * 64) * 1024 + b * 512 + a) * 4;
        float acc[4] = {0.f, 0.f, 0.f, 0.f};
        const f16x2 zero = (f16x2)(f16_t)0.0f;
#define L_A0(i) (*(const f16x4*)(apc + (size_t)(2 * (i)) * 4096))
#define L_A1(i) (*(const f16x4*)(apc + (size_t)(2 * (i) + 1) * 4096))
        constexpr int PF = 4;
        f16x4 pa[PF], pb[PF];
        #pragma unroll
        for (int i = 0; i < PF; ++i) { pa[i] = L_A0(i); pb[i] = L_A1(i); }
        #pragma unroll
        for (int i = 0; i < 32; ++i) {                  // hq pair per iter
            const int sl = i % PF;
            const int hq = 2 * i;
            f16x4 a0 = pa[sl], a1 = pb[sl];
            f16x4 w0 = *(const f16x4*)&w2r[hq * 4];
            f16x4 w1 = *(const f16x4*)&w2r[hq * 4 + 4];
            #pragma unroll
            for (int r = 0; r < 4; ++r) {
                f16x4 t0 = *(const f16x4*)&tpr[r * 1024 + hq * 4];
                f16x4 t1 = *(const f16x4*)&tpr[r * 1024 + hq * 4 + 4];
                f16x2 p;
                p = __builtin_elementwise_max((f16x2){t0[0] + a0[0], t0[1] + a0[1]}, zero);
                acc[r] = dot2_acc(p, (f16x2){w0[0], w0[1]}, acc[r]);
                p = __builtin_elementwise_max((f16x2){t0[2] + a0[2], t0[3] + a0[3]}, zero);
                acc[r] = dot2_acc(p, (f16x2){w0[2], w0[3]}, acc[r]);
                p = __builtin_elementwise_max((f16x2){t1[0] + a1[0], t1[1] + a1[1]}, zero);
                acc[r] = dot2_acc(p, (f16x2){w1[0], w1[1]}, acc[r]);
                p = __builtin_elementwise_max((f16x2){t1[2] + a1[2], t1[3] + a1[3]}, zero);
                acc[r] = dot2_acc(p, (f16x2){w1[2], w1[3]}, acc[r]);
            }
            const int nx = i + PF;
            if (nx < 32) { pa[sl] = L_A0(nx); pb[sl] = L_A1(nx); }
        }
#undef L_A0
#undef L_A1
        float* dst = lp + (size_t)(hc * 256 + bt0) * 512 + a;
        #pragma unroll
        for (int r = 0; r < 4; ++r) dst[(size_t)r * 512] = acc[r];
    }
}

// ---------------------------------------------------------------------------
// combine: blocks [0,256): sum lp chunks + bias + monotonic, softmax -> out.
//          blocks [256,288): conv3 + GN2 (reduced from bstat2) + softplus.
// ---------------------------------------------------------------------------
__global__ __launch_bounds__(512) void combine_k(
    const float* __restrict__ lp, const float* __restrict__ b2,
    const bf16_t* __restrict__ y2, const float* __restrict__ bstat2,
    const float* __restrict__ g, const float* __restrict__ bet,
    const float* __restrict__ w3, const float* __restrict__ b3,
    float* __restrict__ out)
{
    __shared__ float redm[8], redsum[8];
    const int bid = blockIdx.x;
    const int tid = threadIdx.x;
    if (bid < 256) {
        const int bt = bid, t = bt & 127;
        const int a = tid;
        const int lane = a & 63, wid = a >> 6;
        const size_t base = (size_t)bt * 512 + a;
        float v = lp[base] + lp[131072 + base] + lp[262144 + base] + lp[393216 + base];
        v += b2[0] - 0.1f * fabsf((float)a - 4.0f * (float)t);
        float m = v;
        #pragma unroll
        for (int off = 32; off > 0; off >>= 1) m = fmaxf(m, __shfl_xor(m, off));
        if (lane == 0) redm[wid] = m;
        __syncthreads();
        float M = redm[0];
        #pragma unroll
        for (int i = 1; i < 8; ++i) M = fmaxf(M, redm[i]);
        const float e = expf(v - M);
        float s = e;
        #pragma unroll
        for (int off = 32; off > 0; off >>= 1) s += __shfl_xor(s, off);
        if (lane == 0) redsum[wid] = s;
        __syncthreads();
        float S = redsum[0];
        #pragma unroll
        for (int i = 1; i < 8; ++i) S += redsum[i];
        out[(size_t)bt * 512 + a] = e * (1.0f / S);
    } else {
        // conv3 + GN2-fold + softplus; mu/var reduced from conv2 partials.
        const int cb = bid - 256;              // 0..31, bt [cb*8, cb*8+8)
        const int b = (cb * 8) >> 7;
        float mu, rsig;
        reduce_bstat(bstat2, b, tid, redm, redsum, mu, rsig);
        const int lane = tid & 63, w = tid >> 6;
        const int bt = cb * 8 + w;
        const bf16_t* row = y2 + (size_t)bt * 1024 + lane * 16;
        float s1 = 0.f, s2 = 0.f, s3 = 0.f;
        #pragma unroll
        for (int c = 0; c < 2; ++c) {
            bf16x8 yv = *(const bf16x8*)(row + c * 8);
            #pragma unroll
            for (int j = 0; j < 8; ++j) {
                const int i = lane * 16 + c * 8 + j;
                const float gw = g[i] * w3[i];
                s1 += gw * (float)yv[j];
                s2 += gw;
                s3 += bet[i] * w3[i];
            }
        }
        #pragma unroll
        for (int off = 32; off > 0; off >>= 1) {
            s1 += __shfl_xor(s1, off);
            s2 += __shfl_xor(s2, off);
            s3 += __shfl_xor(s3, off);
        }
        if (lane == 0) {
            const float t = rsig * (s1 - mu * s2) + s3 + b3[0];
            out[131072 + bt] = fmaxf(t, 0.f) + log1pf(expf(-fabsf(t)));
        }
    }
}

extern "C" void kernel_launch(void* const* d_in, const int* in_sizes, int n_in,
                              void* d_out, int out_size, void* d_ws, size_t ws_size,
                              hipStream_t stream) {
    const float* text   = (const float*)d_in[0];
    const float* audio  = (const float*)d_in[1];
    const float* a_w1   = (const float*)d_in[2];
    const float* a_b1   = (const float*)d_in[3];
    const float* a_w2   = (const float*)d_in[4];
    const float* a_b2   = (const float*)d_in[5];
    const float* d_w1   = (const float*)d_in[6];
    const float* d_b1   = (const float*)d_in[7];
    const float* gn1_g  = (const float*)d_in[8];
    const float* gn1_b  = (const float*)d_in[9];
    const float* d_w2   = (const float*)d_in[10];
    const float* d_b2   = (const float*)d_in[11];
    const float* gn2_g  = (const float*)d_in[12];
    const float* gn2_b  = (const float*)d_in[13];
    const float* d_w3   = (const float*)d_in[14];
    const float* d_b3   = (const float*)d_in[15];

    char* ws = (char*)d_ws;
    float* outf = (float*)d_out;

    bf16_t* text_bf  = (bf16_t*)(ws + OFF_TEXTBF);
    bf16_t* audio_bf = (bf16_t*)(ws + OFF_AUDIOBF);
    bf16_t* w1topT   = (bf16_t*)(ws + OFF_W1TOP);
    bf16_t* w1botT   = (bf16_t*)(ws + OFF_W1BOT);
    bf16_t* wc1      = (bf16_t*)(ws + OFF_WC1);
    bf16_t* wc2      = (bf16_t*)(ws + OFF_WC2);
    f16_t*  tp       = (f16_t*) (ws + OFF_TP);
    f16_t*  w2f      = (f16_t*) (ws + OFF_W2F);
    f16_t*  apT4     = (f16_t*) (ws + OFF_APT);
    bf16_t* xp0      = (bf16_t*)(ws + OFF_XP0);
    bf16_t* xp1      = (bf16_t*)(ws + OFF_XP1);
    bf16_t* y2       = (bf16_t*)(ws + OFF_Y2);
    float*  bstat1   = (float*) (ws + OFF_BST1);
    float*  bstat2   = (float*) (ws + OFF_BST2);
    float*  lp       = (float*) (ws + OFF_LP);
    float*  Sg3     = (float*) (ws + OFF_SG);
    float*  Sb3     = (float*) (ws + OFF_SB);
    float*  SgFp    = (float*) (ws + OFF_SGF);
    float*  SbFp    = (float*) (ws + OFF_SBF);

    // 1: prep (cvt activations, w1 transpose, conv weights + sums, pads, w2f)
    prep_k<<<dim3(5377), 256, 0, stream>>>(text, audio, a_w1, d_w1, d_w2, a_w2,
                                           gn1_g, gn1_b,
                                           text_bf, xp0, audio_bf, w1topT, w1botT,
                                           wc1, wc2, xp1, w2f, Sg3, Sb3,
                                           SgFp, SbFp);
    // 2: conv1 (512) ∥ tp gemm (256) ∥ ap gemm (1024) — 1792 x 512 thr
    p2_k<<<dim3(1792), 512, 0, stream>>>(wc1, xp0, d_b1, xp1, bstat1,
                                         text_bf, w1topT, a_b1, tp,
                                         audio_bf, w1botT, apT4);
    // 3: conv2 (512, GN1 folded) ∥ logits (256) — 768 x 512 thr
    p3_k<<<dim3(768), 512, 0, stream>>>(wc2, xp1, d_b2, y2, bstat2, bstat1,
                                        SgFp, SbFp, Sg3, Sb3, tp, apT4, w2f, lp);
    // 4: combine+softmax -> alignment; conv3+GN2(reduced)+softplus -> durations
    combine_k<<<dim3(288), 512, 0, stream>>>(lp, a_b2, y2, bstat2,
                                             gn2_g, gn2_b, d_w3, d_b3, outf);
}

// Round 9
// 152.760 us; speedup vs baseline: 1.9297x; 1.2496x over previous
//
#include <hip/hip_runtime.h>
#include <hip/hip_bf16.h>

// ---------------------------------------------------------------------------
// MonotonicAlignmentSearch R21: kill address divergence in MFMA operand
// loads (the R13-R20 invariant: ~45us conv/gemm phases at ~16B/cycle/CU =
// TA processing 1 lane/cyc on 16-row-scattered wave loads).
//  - GEMM operands + conv weights: prep writes them in MFMA-fragment-tile
//    order ([rb][kc][64 lanes x 16B]) => every fragment load is one
//    contiguous 1KB wave read (asm-batched, counted vmcnt).
//  - Conv activations (tap-shifted): staged rows [34][BK=256] into padded
//    LDS [34][264] via row-major coalesced reads; fragments via ds_read_b128
//    (2-way banking = free). 3 taps share one staged buffer.
// Epilogues/stats/logits/combine verbatim R16/R20. B=2,TT=128,TA=512,H=1024.
// ---------------------------------------------------------------------------

typedef __bf16 bf16_t;
typedef __bf16 bf16x8 __attribute__((ext_vector_type(8)));
typedef __bf16 bf16x4 __attribute__((ext_vector_type(4)));
typedef float  f32x4  __attribute__((ext_vector_type(4)));
typedef _Float16 f16_t;
typedef _Float16 f16x2 __attribute__((ext_vector_type(2)));
typedef _Float16 f16x4 __attribute__((ext_vector_type(4)));
typedef int v4i __attribute__((ext_vector_type(4)));

#define EPSV 1e-5f

#define GLD(dst, ptr, off) \
    asm volatile("global_load_dwordx4 %0, %1, off offset:%c2" \
                 : "=v"(dst) : "v"(ptr), "n"(off) : "memory")
#define WAITV(n) do { \
    asm volatile("s_waitcnt vmcnt(%c0)" :: "n"(n) : "memory"); \
    __builtin_amdgcn_sched_barrier(0); } while (0)

__device__ __forceinline__ bf16x8 as_bf16x8(v4i v) {
    union { v4i i; bf16x8 h; } u; u.i = v; return u.h;
}

// ---- workspace offsets (bytes) -------------------------------------------
#define OFF_TEXTP    0u          //  524288  bf16 textP  [16 rb][32 kc][512]
#define OFF_AUDIOP   524288u     // 2097152  bf16 audioP [64 rb][32 kc][512]
#define OFF_W1TOP    2621440u    // 2097152  bf16 topP   [64 rb][32 kc][512]
#define OFF_W1BOT    4718592u    // 2097152  bf16 botP   [64 rb][32 kc][512]
#define OFF_WC1      6815744u    // 6291456  bf16 wc1P [3][64 rb][32 kc][512]
#define OFF_WC2      13107200u   // 6291456  bf16 wc2P (g-scaled)
#define OFF_TP       19398656u   //  524288  f16 tp [256 bt][1024 d]
#define OFF_W2F      19922944u   //    2048  f16 w2 [1024]
#define OFF_APT      20447232u   // 2097152  f16 apT4 [256 hq][1024 ba][4]
#define OFF_XP0      22544384u   //  532480  bf16 xp0 [2][130][1024] row-major
#define OFF_XP1      23076864u   //  532480  bf16 xp1 [2][130][1024] raw relu
#define OFF_Y2       23609344u   //  524288  bf16 y2 [256][1024]
#define OFF_BST1     24133632u   //    4096  f32 bstat1 [512][2]
#define OFF_BST2     24137728u   //    4096  f32 bstat2 [512][2]
#define OFF_LP       24141824u   // 2097152  f32 lp [4][256][512]
#define OFF_SG       26238976u   //   12288  f32 Sg3 [1024][3]
#define OFF_SB       26251264u   //   12288  f32 Sb3 [1024][3]
#define OFF_SGF      26263552u   //    4096  f32 SgF [1024]
#define OFF_SBF      26267648u   //    4096  f32 SbF [1024]

// ---------------------------------------------------------------------------
// prep: [0,1280) act cvt (xp0 row-major + textP/audioP fragment-packed);
// [1280,3328) w1 transpose -> fragment-packed topP/botP;
// [3328,5376) conv weights -> fragment-packed (+ Sg/Sb sums);
// 5376: zero pads + w2->f16.
// ---------------------------------------------------------------------------
__global__ __launch_bounds__(256) void prep_k(
    const float* __restrict__ text, const float* __restrict__ audio,
    const float* __restrict__ w1,
    const float* __restrict__ w1c, const float* __restrict__ w2c,
    const float* __restrict__ w2,
    const float* __restrict__ g1, const float* __restrict__ b1g,
    bf16_t* __restrict__ textP, bf16_t* __restrict__ xp0,
    bf16_t* __restrict__ audioP,
    bf16_t* __restrict__ topP, bf16_t* __restrict__ botP,
    bf16_t* __restrict__ wc1, bf16_t* __restrict__ wc2,
    bf16_t* __restrict__ xp1, f16_t* __restrict__ w2f,
    float* __restrict__ Sg, float* __restrict__ Sb,
    float* __restrict__ SgF, float* __restrict__ SbF)
{
    __shared__ float tile[32][33];
    const int bid = blockIdx.x;
    if (bid < 1280) {
        const int e = (bid * 256 + threadIdx.x) * 4;   // 1310720 total
        if (e < 262144) {
            float4 v = *(const float4*)&text[e];
            bf16x4 o; o[0] = (bf16_t)v.x; o[1] = (bf16_t)v.y; o[2] = (bf16_t)v.z; o[3] = (bf16_t)v.w;
            const int bt = e >> 10, h = e & 1023;
            const int b = bt >> 7, t = bt & 127;
            *(bf16x4*)&xp0[(size_t)(b * 130 + 1 + t) * 1024 + h] = o;
            const int lane = (bt & 15) | (((h >> 3) & 3) << 4);
            *(bf16x4*)&textP[((size_t)((bt >> 4) * 32 + (h >> 5))) * 512 + lane * 8 + (h & 7)] = o;
        } else {
            const int ea = e - 262144;
            float4 v = *(const float4*)&audio[ea];
            bf16x4 o; o[0] = (bf16_t)v.x; o[1] = (bf16_t)v.y; o[2] = (bf16_t)v.z; o[3] = (bf16_t)v.w;
            const int ba = ea >> 10, h = ea & 1023;
            const int lane = (ba & 15) | (((h >> 3) & 3) << 4);
            *(bf16x4*)&audioP[((size_t)((ba >> 4) * 32 + (h >> 5))) * 512 + lane * 8 + (h & 7)] = o;
        }
    } else if (bid < 3328) {
        const int b2 = bid - 1280;
        const int bx = b2 & 31, by = b2 >> 5;          // bx: d-blk(32), by: h-blk(64)
        const int tx = threadIdx.x & 31, ty = threadIdx.x >> 5;
        #pragma unroll
        for (int j = 0; j < 4; ++j)
            tile[ty + j * 8][tx] = w1[(size_t)(by * 32 + ty + j * 8) * 1024 + bx * 32 + tx];
        __syncthreads();
        // tile[h_local][d_local]; packed out: (d,h) -> tile (d>>4)*32+(h>>5), lane (d&15)|((h>>3&3)<<4), elem h&7
        if (threadIdx.x < 128) {
            const int rbl = threadIdx.x >> 6, lane = threadIdx.x & 63;
            const int dl = rbl * 16 + (lane & 15);
            const int lkp = lane >> 4;
            bf16x8 v8;
            #pragma unroll
            for (int e2 = 0; e2 < 8; ++e2) v8[e2] = (bf16_t)tile[lkp * 8 + e2][dl];
            const int d = bx * 32 + dl;
            bf16_t* out = (by < 32) ? topP : botP;
            *(bf16x8*)&out[((size_t)((d >> 4) * 32 + (by & 31))) * 512 + lane * 8] = v8;
        }
    } else if (bid < 5376) {
        int b2 = bid - 3328;
        const int is2 = (b2 >= 1024) ? 1 : 0;
        const float* w = is2 ? w2c : w1c;
        bf16_t* wc = is2 ? wc2 : wc1;
        b2 &= 1023;
        const int o = b2, i4 = threadIdx.x;            // one block per out-chan
        const float* src = w + (size_t)o * 3072 + i4 * 12;
        float4 v0 = *(const float4*)&src[0];
        float4 v1 = *(const float4*)&src[4];
        float4 v2 = *(const float4*)&src[8];
        const float f[12] = {v0.x, v0.y, v0.z, v0.w, v1.x, v1.y, v1.z, v1.w, v2.x, v2.y, v2.z, v2.w};
        float g4[4] = {1.f, 1.f, 1.f, 1.f}, bb4[4] = {0.f, 0.f, 0.f, 0.f};
        if (is2) {
            float4 gv = *(const float4*)&g1[i4 * 4];
            float4 bv = *(const float4*)&b1g[i4 * 4];
            g4[0] = gv.x; g4[1] = gv.y; g4[2] = gv.z; g4[3] = gv.w;
            bb4[0] = bv.x; bb4[1] = bv.y; bb4[2] = bv.z; bb4[3] = bv.w;
        }
        const int i0 = i4 * 4;
        const int lane = (o & 15) | (((i0 >> 3) & 3) << 4);
        float sgr[3] = {0.f, 0.f, 0.f}, sbr[3] = {0.f, 0.f, 0.f};
        #pragma unroll
        for (int r = 0; r < 3; ++r) {
            bf16x4 o4;
            #pragma unroll
            for (int j = 0; j < 4; ++j) {
                const float wv = f[j * 3 + r];
                const float ws = wv * g4[j];
                sgr[r] += ws;
                sbr[r] += wv * bb4[j];
                o4[j] = (bf16_t)(is2 ? ws : wv);
            }
            *(bf16x4*)&wc[((size_t)(r * 2048 + (o >> 4) * 32 + (i0 >> 5))) * 512 + lane * 8 + (i0 & 7)] = o4;
        }
        if (is2) {
            #pragma unroll
            for (int off = 32; off > 0; off >>= 1) {
                #pragma unroll
                for (int r = 0; r < 3; ++r) {
                    sgr[r] += __shfl_xor(sgr[r], off);
                    sbr[r] += __shfl_xor(sbr[r], off);
                }
            }
            float* red = &tile[0][0];
            const int wid = threadIdx.x >> 6, lane2 = threadIdx.x & 63;
            if (lane2 == 0) {
                #pragma unroll
                for (int r = 0; r < 3; ++r) {
                    red[wid * 6 + r] = sgr[r];
                    red[wid * 6 + 3 + r] = sbr[r];
                }
            }
            __syncthreads();
            if (threadIdx.x < 6) {
                const float v = red[threadIdx.x] + red[6 + threadIdx.x]
                              + red[12 + threadIdx.x] + red[18 + threadIdx.x];
                if (threadIdx.x < 3) Sg[o * 3 + threadIdx.x] = v;
                else                 Sb[o * 3 + threadIdx.x - 3] = v;
                red[24 + threadIdx.x] = v;
            }
            __syncthreads();
            if (threadIdx.x == 0)      SgF[o] = red[24] + red[25] + red[26];
            else if (threadIdx.x == 1) SbF[o] = red[27] + red[28] + red[29];
        }
    } else {
        const int tid = threadIdx.x;
        const int rowmap[4] = {0, 129, 130, 259};
        const int f = tid * 16;
        const int r = f >> 10, w = f & 1023;
        bf16x8 z8 = (bf16x8)(bf16_t)0.0f;
        bf16_t* p0 = xp0 + (size_t)rowmap[r] * 1024 + w;
        bf16_t* p1 = xp1 + (size_t)rowmap[r] * 1024 + w;
        *(bf16x8*)p0 = z8; *(bf16x8*)(p0 + 8) = z8;
        *(bf16x8*)p1 = z8; *(bf16x8*)(p1 + 8) = z8;
        float4 wv = *(const float4*)&w2[tid * 4];
        f16x4 wo; wo[0] = (f16_t)wv.x; wo[1] = (f16_t)wv.y; wo[2] = (f16_t)wv.z; wo[3] = (f16_t)wv.w;
        *(f16x4*)&w2f[tid * 4] = wo;
    }
}

// ---------------------------------------------------------------------------
// helpers
// ---------------------------------------------------------------------------
__device__ __forceinline__ float wave_red_add(float v) {
    #pragma unroll
    for (int off = 32; off > 0; off >>= 1) v += __shfl_xor(v, off);
    return v;
}

// Conv MFMA body: block = 16 chans x 32 bt; activations staged in LDS
// (rows tbase..tbase+33, K-chunks of 256, padded stride 264); weights
// fragment-packed, contiguous 1KB loads. Wave w covers cols c*256+w*32.
// Leaves per-wave partials in acc0/acc1 (full K covered by 8 waves x 4 c).
__device__ __forceinline__ void conv_body(
    const bf16_t* __restrict__ WcP, const bf16_t* __restrict__ xp,
    int by, int b, int tbase, int w, int l, bf16_t* Bs, int tid,
    f32x4& acc0, f32x4& acc1)
{
    const int lm = l & 15, lk = (l >> 4) * 8;
    const bf16_t* xrow = xp + (size_t)(b * 130 + tbase) * 1024;
    #pragma unroll 1
    for (int c = 0; c < 4; ++c) {
        __syncthreads();
        for (int idx = tid; idx < 1088; idx += 512) {
            const int row = idx >> 5, col = (idx & 31) * 8;
            *(v4i*)&Bs[row * 264 + col] =
                *(const v4i*)&xrow[(size_t)row * 1024 + c * 256 + col];
        }
        __syncthreads();
        const int kc = c * 8 + w;
        const bf16_t* a0 = WcP + ((size_t)(by * 32 + kc)) * 512 + l * 8;
        v4i A0, A1, A2;
        GLD(A0, a0, 0);
        GLD(A1, a0 + 1048576, 0);
        GLD(A2, a0 + 2097152, 0);
        const int cb = w * 32 + lk;
        bf16x8 b00 = *(const bf16x8*)&Bs[(lm + 0) * 264 + cb];
        bf16x8 b10 = *(const bf16x8*)&Bs[(lm + 16) * 264 + cb];
        bf16x8 b01 = *(const bf16x8*)&Bs[(lm + 1) * 264 + cb];
        bf16x8 b11 = *(const bf16x8*)&Bs[(lm + 17) * 264 + cb];
        bf16x8 b02 = *(const bf16x8*)&Bs[(lm + 2) * 264 + cb];
        bf16x8 b12 = *(const bf16x8*)&Bs[(lm + 18) * 264 + cb];
        WAITV(2);
        acc0 = __builtin_amdgcn_mfma_f32_16x16x32_bf16(as_bf16x8(A0), b00, acc0, 0, 0, 0);
        acc1 = __builtin_amdgcn_mfma_f32_16x16x32_bf16(as_bf16x8(A0), b10, acc1, 0, 0, 0);
        WAITV(1);
        acc0 = __builtin_amdgcn_mfma_f32_16x16x32_bf16(as_bf16x8(A1), b01, acc0, 0, 0, 0);
        acc1 = __builtin_amdgcn_mfma_f32_16x16x32_bf16(as_bf16x8(A1), b11, acc1, 0, 0, 0);
        WAITV(0);
        acc0 = __builtin_amdgcn_mfma_f32_16x16x32_bf16(as_bf16x8(A2), b02, acc0, 0, 0, 0);
        acc1 = __builtin_amdgcn_mfma_f32_16x16x32_bf16(as_bf16x8(A2), b12, acc1, 0, 0, 0);
    }
    __syncthreads();   // Bs reads done; LDS may be reused as float reduce area
}

// ---------------------------------------------------------------------------
// P2: blocks [0,512) conv1 tiles; [512,768) tp gemm; [768,1792) ap gemm.
// ---------------------------------------------------------------------------
__global__ __launch_bounds__(512) void p2_k(
    const bf16_t* __restrict__ wc1, const bf16_t* __restrict__ xp0,
    const float* __restrict__ d_b1, bf16_t* __restrict__ xp1,
    float* __restrict__ bstat1,
    const bf16_t* __restrict__ textP, const bf16_t* __restrict__ topP,
    const float* __restrict__ a_b1, f16_t* __restrict__ tp,
    const bf16_t* __restrict__ audioP, const bf16_t* __restrict__ botP,
    f16_t* __restrict__ apT4)
{
    __shared__ float smem[8448];                 // conv: Bs bf16[34][264] then reduce; gemm: [8][32][33]
    __shared__ float sred[8], sredq[8];
    const int bid = blockIdx.x;
    const int tid = threadIdx.x;
    const int w = tid >> 6, l = tid & 63;
    const int lm = l & 15, lh = l >> 4;
    if (bid < 512) {
        const int bx = bid >> 6, by = bid & 63;
        const int bt0 = bx * 32, m0 = by * 16;
        const int b = bt0 >> 7, tbase = bt0 & 127;
        f32x4 acc0 = (f32x4)(0.0f), acc1 = (f32x4)(0.0f);
        conv_body(wc1, xp0, by, b, tbase, w, l, (bf16_t*)smem, tid, acc0, acc1);
        float* sl = smem + w * 528;
        #pragma unroll
        for (int r = 0; r < 4; ++r) {
            sl[(lh * 4 + r) * 33 + lm] = acc0[r];
            sl[(lh * 4 + r) * 33 + 16 + lm] = acc1[r];
        }
        __syncthreads();
        const int mm = tid >> 5, nn = tid & 31;  // chan-local, bt-local
        float v = 0.f;
        #pragma unroll
        for (int ww = 0; ww < 8; ++ww) v += smem[ww * 528 + mm * 33 + nn];
        v = fmaxf(v + d_b1[m0 + mm], 0.f);
        float s = wave_red_add(v), q = wave_red_add(v * v);
        if (l == 0) { sred[w] = s; sredq[w] = q; }
        xp1[(size_t)(b * 130 + 1 + tbase + nn) * 1024 + m0 + mm] = (bf16_t)v;
        __syncthreads();
        if (tid == 0) {
            float ts = 0.f, tq = 0.f;
            #pragma unroll
            for (int ww = 0; ww < 8; ++ww) { ts += sred[ww]; tq += sredq[ww]; }
            bstat1[bid * 2] = ts; bstat1[bid * 2 + 1] = tq;
        }
    } else {
        // gemm 32x32 tile, 8-way K-split; fragment-packed operands.
        const bf16_t *At, *Bm;
        int d0, r0, is_tp;
        if (bid < 768) {
            const int unit = bid - 512;          // 256 units: 8 bt x 32 d
            d0 = (unit & 31) * 32; r0 = (unit >> 5) * 32;
            At = topP; Bm = textP; is_tp = 1;
        } else {
            const int unit = bid - 768;          // 1024 units: 32 a x 32 d
            d0 = (unit & 31) * 32; r0 = (unit >> 5) * 32;
            At = botP; Bm = audioP; is_tp = 0;
        }
        const int rb0 = d0 >> 4, rbB = r0 >> 4;
        const bf16_t* Ap0 = At + ((size_t)(rb0 * 32 + w * 4)) * 512 + l * 8;
        const bf16_t* Ap1 = Ap0 + 16384;
        const bf16_t* Bp0 = Bm + ((size_t)(rbB * 32 + w * 4)) * 512 + l * 8;
        const bf16_t* Bp1 = Bp0 + 16384;
        v4i qa0[4], qa1[4], qb0[4], qb1[4];
        GLD(qa0[0], Ap0,    0); GLD(qa1[0], Ap1,    0); GLD(qb0[0], Bp0,    0); GLD(qb1[0], Bp1,    0);
        GLD(qa0[1], Ap0, 1024); GLD(qa1[1], Ap1, 1024); GLD(qb0[1], Bp0, 1024); GLD(qb1[1], Bp1, 1024);
        GLD(qa0[2], Ap0, 2048); GLD(qa1[2], Ap1, 2048); GLD(qb0[2], Bp0, 2048); GLD(qb1[2], Bp1, 2048);
        GLD(qa0[3], Ap0, 3072); GLD(qa1[3], Ap1, 3072); GLD(qb0[3], Bp0, 3072); GLD(qb1[3], Bp1, 3072);
        f32x4 acc[2][2];
        #pragma unroll
        for (int mt = 0; mt < 2; ++mt)
            #pragma unroll
            for (int nt = 0; nt < 2; ++nt) acc[mt][nt] = (f32x4)(0.0f);
#define GMF(cc, n) \
        WAITV(n); \
        acc[0][0] = __builtin_amdgcn_mfma_f32_16x16x32_bf16(as_bf16x8(qa0[cc]), as_bf16x8(qb0[cc]), acc[0][0], 0, 0, 0); \
        acc[0][1] = __builtin_amdgcn_mfma_f32_16x16x32_bf16(as_bf16x8(qa0[cc]), as_bf16x8(qb1[cc]), acc[0][1], 0, 0, 0); \
        acc[1][0] = __builtin_amdgcn_mfma_f32_16x16x32_bf16(as_bf16x8(qa1[cc]), as_bf16x8(qb0[cc]), acc[1][0], 0, 0, 0); \
        acc[1][1] = __builtin_amdgcn_mfma_f32_16x16x32_bf16(as_bf16x8(qa1[cc]), as_bf16x8(qb1[cc]), acc[1][1], 0, 0, 0)
        GMF(0, 12); GMF(1, 8); GMF(2, 4); GMF(3, 0);
#undef GMF
        float* sl = smem + w * 1056;
        #pragma unroll
        for (int mt = 0; mt < 2; ++mt)
            #pragma unroll
            for (int nt = 0; nt < 2; ++nt)
                #pragma unroll
                for (int r = 0; r < 4; ++r)
                    sl[(mt * 16 + lh * 4 + r) * 33 + nt * 16 + lm] = acc[mt][nt][r];
        __syncthreads();
        const int m = tid >> 4, n2 = (tid & 15) * 2;     // d-local, row-local pair
        float v0 = 0.f, v1 = 0.f;
        #pragma unroll
        for (int ww = 0; ww < 8; ++ww) {
            v0 += smem[ww * 1056 + m * 33 + n2];
            v1 += smem[ww * 1056 + m * 33 + n2 + 1];
        }
        if (is_tp) {
            const float bb = a_b1[d0 + m];
            tp[(size_t)(r0 + n2) * 1024 + d0 + m] = (f16_t)(v0 + bb);
            tp[(size_t)(r0 + n2 + 1) * 1024 + d0 + m] = (f16_t)(v1 + bb);
        } else {
            const int h = d0 + m, hq = h >> 2, hr = h & 3;
            const int a0 = r0 + n2;
            const int bbk = a0 >> 9, al = a0 & 511;
            apT4[((size_t)hq * 1024 + bbk * 512 + al) * 4 + hr] = (f16_t)v0;
            apT4[((size_t)hq * 1024 + bbk * 512 + al + 1) * 4 + hr] = (f16_t)v1;
        }
    }
}

// reduce 256 (s,q) pairs for batch b from bstat (block-level, 512 threads).
__device__ __forceinline__ void reduce_bstat(
    const float* __restrict__ bstat, int b, int tid,
    float* sr, float* sq, float& mu, float& rsig)
{
    const int lane = tid & 63, wid = tid >> 6;
    float s = 0.f, q = 0.f;
    if (tid < 256) {
        float2 v = ((const float2*)bstat)[b * 256 + tid];
        s = v.x; q = v.y;
    }
    #pragma unroll
    for (int off = 32; off > 0; off >>= 1) {
        s += __shfl_xor(s, off);
        q += __shfl_xor(q, off);
    }
    if (lane == 0) { sr[wid] = s; sq[wid] = q; }
    __syncthreads();
    float ts = 0.f, tq = 0.f;
    #pragma unroll
    for (int i = 0; i < 8; ++i) { ts += sr[i]; tq += sq[i]; }
    const float cnt = 131072.f;
    mu = ts / cnt;
    const float var = tq / cnt - mu * mu;
    rsig = rsqrtf(var + EPSV);
}

// ---------------------------------------------------------------------------
// P3: blocks [0,512) conv2 tiles (GN1 folded); [512,768) logits blocks.
// ---------------------------------------------------------------------------
__device__ __forceinline__ float dot2_acc(f16x2 x, f16x2 w, float acc) {
#if __has_builtin(__builtin_amdgcn_fdot2)
    return __builtin_amdgcn_fdot2(x, w, acc, false);
#else
    return acc + (float)x[0] * (float)w[0] + (float)x[1] * (float)w[1];
#endif
}

__global__ __launch_bounds__(512) void p3_k(
    const bf16_t* __restrict__ wc2, const bf16_t* __restrict__ xp1,
    const float* __restrict__ d_b2, bf16_t* __restrict__ y2,
    float* __restrict__ bstat2, const float* __restrict__ bstat1,
    const float* __restrict__ SgF, const float* __restrict__ SbF,
    const float* __restrict__ Sg3, const float* __restrict__ Sb3,
    const f16_t* __restrict__ tp, const f16_t* __restrict__ apT4,
    const f16_t* __restrict__ w2f, float* __restrict__ lp)
{
    __shared__ float smem[4608];                 // conv: Bs bf16[34][264] then [8][16][33]
    __shared__ float sred[8], sredq[8], sr[8], sq[8];
    const int bid = blockIdx.x;
    const int tid = threadIdx.x;
    if (bid < 512) {
        const int w = tid >> 6, l = tid & 63;
        const int lm = l & 15, lh = l >> 4;
        const int bx = bid >> 6, by = bid & 63;
        const int bt0 = bx * 32, m0 = by * 16;
        const int b = bt0 >> 7, tbase = bt0 & 127;
        f32x4 acc0 = (f32x4)(0.0f), acc1 = (f32x4)(0.0f);
        conv_body(wc2, xp1, by, b, tbase, w, l, (bf16_t*)smem, tid, acc0, acc1);
        float* sl = smem + w * 528;
        #pragma unroll
        for (int r = 0; r < 4; ++r) {
            sl[(lh * 4 + r) * 33 + lm] = acc0[r];
            sl[(lh * 4 + r) * 33 + 16 + lm] = acc1[r];
        }
        __syncthreads();
        const int mm = tid >> 5, nn = tid & 31;
        float vraw = 0.f;
        #pragma unroll
        for (int ww = 0; ww < 8; ++ww) vraw += smem[ww * 528 + mm * 33 + nn];
        float mu, rsig;
        reduce_bstat(bstat1, b, tid, sr, sq, mu, rsig);   // has its own barrier
        const int o = m0 + mm, tloc = tbase + nn;
        float sg = SgF[o], sb = SbF[o];
        if (tloc == 0)   { sg -= Sg3[o * 3];     sb -= Sb3[o * 3]; }
        if (tloc == 127) { sg -= Sg3[o * 3 + 2]; sb -= Sb3[o * 3 + 2]; }
        float v = fmaxf(rsig * vraw + sb - mu * rsig * sg + d_b2[o], 0.f);
        float s = wave_red_add(v), q = wave_red_add(v * v);
        if ((tid & 63) == 0) { sred[tid >> 6] = s; sredq[tid >> 6] = q; }
        y2[(size_t)(b * 128 + tloc) * 1024 + o] = (bf16_t)v;
        __syncthreads();
        if (tid == 0) {
            float ts = 0.f, tq = 0.f;
            #pragma unroll
            for (int ww = 0; ww < 8; ++ww) { ts += sred[ww]; tq += sredq[ww]; }
            bstat2[bid * 2] = ts; bstat2[bid * 2 + 1] = tq;
        }
    } else {
        const int lb = bid - 512;                       // 256 blocks
        const int hc = lb >> 6, btp = lb & 63;
        const int bt0 = btp * 4;
        const int b = bt0 >> 7;
        const int a = tid;                              // 0..511
        const f16_t* tpr = tp + (size_t)bt0 * 1024 + hc * 256;   // wave-uniform
        const f16_t* w2r = w2f + hc * 256;
        const f16_t* apc = apT4 + ((size_t)(hc * 64) * 1024 + b * 512 + a) * 4;
        float acc[4] = {0.f, 0.f, 0.f, 0.f};
        const f16x2 zero = (f16x2)(f16_t)0.0f;
#define L_A0(i) (*(const f16x4*)(apc + (size_t)(2 * (i)) * 4096))
#define L_A1(i) (*(const f16x4*)(apc + (size_t)(2 * (i) + 1) * 4096))
        constexpr int PF = 4;
        f16x4 pa[PF], pb[PF];
        #pragma unroll
        for (int i = 0; i < PF; ++i) { pa[i] = L_A0(i); pb[i] = L_A1(i); }
        #pragma unroll
        for (int i = 0; i < 32; ++i) {                  // hq pair per iter
            const int sl = i % PF;
            const int hq = 2 * i;
            f16x4 a0 = pa[sl], a1 = pb[sl];
            f16x4 w0 = *(const f16x4*)&w2r[hq * 4];
            f16x4 w1 = *(const f16x4*)&w2r[hq * 4 + 4];
            #pragma unroll
            for (int r = 0; r < 4; ++r) {
                f16x4 t0 = *(const f16x4*)&tpr[r * 1024 + hq * 4];
                f16x4 t1 = *(const f16x4*)&tpr[r * 1024 + hq * 4 + 4];
                f16x2 p;
                p = __builtin_elementwise_max((f16x2){t0[0] + a0[0], t0[1] + a0[1]}, zero);
                acc[r] = dot2_acc(p, (f16x2){w0[0], w0[1]}, acc[r]);
                p = __builtin_elementwise_max((f16x2){t0[2] + a0[2], t0[3] + a0[3]}, zero);
                acc[r] = dot2_acc(p, (f16x2){w0[2], w0[3]}, acc[r]);
                p = __builtin_elementwise_max((f16x2){t1[0] + a1[0], t1[1] + a1[1]}, zero);
                acc[r] = dot2_acc(p, (f16x2){w1[0], w1[1]}, acc[r]);
                p = __builtin_elementwise_max((f16x2){t1[2] + a1[2], t1[3] + a1[3]}, zero);
                acc[r] = dot2_acc(p, (f16x2){w1[2], w1[3]}, acc[r]);
            }
            const int nx = i + PF;
            if (nx < 32) { pa[sl] = L_A0(nx); pb[sl] = L_A1(nx); }
        }
#undef L_A0
#undef L_A1
        float* dst = lp + (size_t)(hc * 256 + bt0) * 512 + a;
        #pragma unroll
        for (int r = 0; r < 4; ++r) dst[(size_t)r * 512] = acc[r];
    }
}

// ---------------------------------------------------------------------------
// combine: blocks [0,256): softmax; [256,288): conv3 + GN2 + softplus.
// ---------------------------------------------------------------------------
__global__ __launch_bounds__(512) void combine_k(
    const float* __restrict__ lp, const float* __restrict__ b2,
    const bf16_t* __restrict__ y2, const float* __restrict__ bstat2,
    const float* __restrict__ g, const float* __restrict__ bet,
    const float* __restrict__ w3, const float* __restrict__ b3,
    float* __restrict__ out)
{
    __shared__ float redm[8], redsum[8];
    const int bid = blockIdx.x;
    const int tid = threadIdx.x;
    if (bid < 256) {
        const int bt = bid, t = bt & 127;
        const int a = tid;
        const int lane = a & 63, wid = a >> 6;
        const size_t base = (size_t)bt * 512 + a;
        float v = lp[base] + lp[131072 + base] + lp[262144 + base] + lp[393216 + base];
        v += b2[0] - 0.1f * fabsf((float)a - 4.0f * (float)t);
        float m = v;
        #pragma unroll
        for (int off = 32; off > 0; off >>= 1) m = fmaxf(m, __shfl_xor(m, off));
        if (lane == 0) redm[wid] = m;
        __syncthreads();
        float M = redm[0];
        #pragma unroll
        for (int i = 1; i < 8; ++i) M = fmaxf(M, redm[i]);
        const float e = expf(v - M);
        float s = e;
        #pragma unroll
        for (int off = 32; off > 0; off >>= 1) s += __shfl_xor(s, off);
        if (lane == 0) redsum[wid] = s;
        __syncthreads();
        float S = redsum[0];
        #pragma unroll
        for (int i = 1; i < 8; ++i) S += redsum[i];
        out[(size_t)bt * 512 + a] = e * (1.0f / S);
    } else {
        const int cb = bid - 256;              // 0..31, bt [cb*8, cb*8+8)
        const int b = (cb * 8) >> 7;
        float mu, rsig;
        reduce_bstat(bstat2, b, tid, redm, redsum, mu, rsig);
        const int lane = tid & 63, w = tid >> 6;
        const int bt = cb * 8 + w;
        const bf16_t* row = y2 + (size_t)bt * 1024 + lane * 16;
        float s1 = 0.f, s2 = 0.f, s3 = 0.f;
        #pragma unroll
        for (int c = 0; c < 2; ++c) {
            bf16x8 yv = *(const bf16x8*)(row + c * 8);
            #pragma unroll
            for (int j = 0; j < 8; ++j) {
                const int i = lane * 16 + c * 8 + j;
                const float gw = g[i] * w3[i];
                s1 += gw * (float)yv[j];
                s2 += gw;
                s3 += bet[i] * w3[i];
            }
        }
        #pragma unroll
        for (int off = 32; off > 0; off >>= 1) {
            s1 += __shfl_xor(s1, off);
            s2 += __shfl_xor(s2, off);
            s3 += __shfl_xor(s3, off);
        }
        if (lane == 0) {
            const float t = rsig * (s1 - mu * s2) + s3 + b3[0];
            out[131072 + bt] = fmaxf(t, 0.f) + log1pf(expf(-fabsf(t)));
        }
    }
}

extern "C" void kernel_launch(void* const* d_in, const int* in_sizes, int n_in,
                              void* d_out, int out_size, void* d_ws, size_t ws_size,
                              hipStream_t stream) {
    const float* text   = (const float*)d_in[0];
    const float* audio  = (const float*)d_in[1];
    const float* a_w1   = (const float*)d_in[2];
    const float* a_b1   = (const float*)d_in[3];
    const float* a_w2   = (const float*)d_in[4];
    const float* a_b2   = (const float*)d_in[5];
    const float* d_w1   = (const float*)d_in[6];
    const float* d_b1   = (const float*)d_in[7];
    const float* gn1_g  = (const float*)d_in[8];
    const float* gn1_b  = (const float*)d_in[9];
    const float* d_w2   = (const float*)d_in[10];
    const float* d_b2   = (const float*)d_in[11];
    const float* gn2_g  = (const float*)d_in[12];
    const float* gn2_b  = (const float*)d_in[13];
    const float* d_w3   = (const float*)d_in[14];
    const float* d_b3   = (const float*)d_in[15];

    char* ws = (char*)d_ws;
    float* outf = (float*)d_out;

    bf16_t* textP    = (bf16_t*)(ws + OFF_TEXTP);
    bf16_t* audioP   = (bf16_t*)(ws + OFF_AUDIOP);
    bf16_t* topP     = (bf16_t*)(ws + OFF_W1TOP);
    bf16_t* botP     = (bf16_t*)(ws + OFF_W1BOT);
    bf16_t* wc1      = (bf16_t*)(ws + OFF_WC1);
    bf16_t* wc2      = (bf16_t*)(ws + OFF_WC2);
    f16_t*  tp       = (f16_t*) (ws + OFF_TP);
    f16_t*  w2f      = (f16_t*) (ws + OFF_W2F);
    f16_t*  apT4     = (f16_t*) (ws + OFF_APT);
    bf16_t* xp0      = (bf16_t*)(ws + OFF_XP0);
    bf16_t* xp1      = (bf16_t*)(ws + OFF_XP1);
    bf16_t* y2       = (bf16_t*)(ws + OFF_Y2);
    float*  bstat1   = (float*) (ws + OFF_BST1);
    float*  bstat2   = (float*) (ws + OFF_BST2);
    float*  lp       = (float*) (ws + OFF_LP);
    float*  Sg3      = (float*) (ws + OFF_SG);
    float*  Sb3      = (float*) (ws + OFF_SB);
    float*  SgFp     = (float*) (ws + OFF_SGF);
    float*  SbFp     = (float*) (ws + OFF_SBF);

    // 1: prep (fragment-pack operands, xp0 row-major, sums, pads, w2f)
    prep_k<<<dim3(5377), 256, 0, stream>>>(text, audio, a_w1, d_w1, d_w2, a_w2,
                                           gn1_g, gn1_b,
                                           textP, xp0, audioP, topP, botP,
                                           wc1, wc2, xp1, w2f, Sg3, Sb3,
                                           SgFp, SbFp);
    // 2: conv1 (512) ∥ tp gemm (256) ∥ ap gemm (1024) — 1792 x 512 thr
    p2_k<<<dim3(1792), 512, 0, stream>>>(wc1, xp0, d_b1, xp1, bstat1,
                                         textP, topP, a_b1, tp,
                                         audioP, botP, apT4);
    // 3: conv2 (512, GN1 folded) ∥ logits (256) — 768 x 512 thr
    p3_k<<<dim3(768), 512, 0, stream>>>(wc2, xp1, d_b2, y2, bstat2, bstat1,
                                        SgFp, SbFp, Sg3, Sb3, tp, apT4, w2f, lp);
    // 4: combine+softmax -> alignment; conv3+GN2(reduced)+softplus -> durations
    combine_k<<<dim3(288), 512, 0, stream>>>(lp, a_b2, y2, bstat2,
                                             gn2_g, gn2_b, d_w3, d_b3, outf);
}

// Round 10
// 150.585 us; speedup vs baseline: 1.9576x; 1.0144x over previous
//
#include <hip/hip_runtime.h>
#include <hip/hip_bf16.h>

// ---------------------------------------------------------------------------
// MonotonicAlignmentSearch R22: R21 (152.8us, divergence-fixed) + three
// surgical changes:
//  1) pair-coalesced packed STORES in prep (act-pack, w-pack): thread pairs
//     (2k,2k+1) share one 16B chunk -> shfl_down merge, even lanes store 16B.
//  2) wc2-pack + Sg/Sb moved from prep into p2's grid (512 two-chan blocks):
//     12MB of reads overlap conv1/gemm instead of serializing in prep.
//  3) conv_body issues weight GLDs before the LDS staging loop (latency
//     hides under staging; vmcnt retires in order so counted waits stay safe).
// B=2, TT=128, TA=512, H=1024.
// ---------------------------------------------------------------------------

typedef __bf16 bf16_t;
typedef __bf16 bf16x8 __attribute__((ext_vector_type(8)));
typedef __bf16 bf16x4 __attribute__((ext_vector_type(4)));
typedef float  f32x4  __attribute__((ext_vector_type(4)));
typedef _Float16 f16_t;
typedef _Float16 f16x2 __attribute__((ext_vector_type(2)));
typedef _Float16 f16x4 __attribute__((ext_vector_type(4)));
typedef int v4i __attribute__((ext_vector_type(4)));

#define EPSV 1e-5f

#define GLD(dst, ptr, off) \
    asm volatile("global_load_dwordx4 %0, %1, off offset:%c2" \
                 : "=v"(dst) : "v"(ptr), "n"(off) : "memory")
#define WAITV(n) do { \
    asm volatile("s_waitcnt vmcnt(%c0)" :: "n"(n) : "memory"); \
    __builtin_amdgcn_sched_barrier(0); } while (0)

__device__ __forceinline__ bf16x8 as_bf16x8(v4i v) {
    union { v4i i; bf16x8 h; } u; u.i = v; return u.h;
}

// pair-coalesced 16B store: pairs (2k,2k+1) share one chunk; even lane
// stores elems 0-3 (own) + 4-7 (odd partner's) as one aligned v4i.
__device__ __forceinline__ void pair_store16(bf16_t* even_addr, bf16x4 v, int t) {
    union { bf16x4 h; unsigned u[2]; } a; a.h = v;
    const unsigned ox = __shfl_down(a.u[0], 1);
    const unsigned oy = __shfl_down(a.u[1], 1);
    if (!(t & 1)) {
        union { unsigned u[4]; v4i i; } o;
        o.u[0] = a.u[0]; o.u[1] = a.u[1]; o.u[2] = ox; o.u[3] = oy;
        *(v4i*)even_addr = o.i;
    }
}

// ---- workspace offsets (bytes) -------------------------------------------
#define OFF_TEXTP    0u          //  524288  bf16 textP  [16 rb][32 kc][512]
#define OFF_AUDIOP   524288u     // 2097152  bf16 audioP [64 rb][32 kc][512]
#define OFF_W1TOP    2621440u    // 2097152  bf16 topP   [64 rb][32 kc][512]
#define OFF_W1BOT    4718592u    // 2097152  bf16 botP   [64 rb][32 kc][512]
#define OFF_WC1      6815744u    // 6291456  bf16 wc1P [3][64 rb][32 kc][512]
#define OFF_WC2      13107200u   // 6291456  bf16 wc2P (g-scaled)
#define OFF_TP       19398656u   //  524288  f16 tp [256 bt][1024 d]
#define OFF_W2F      19922944u   //    2048  f16 w2 [1024]
#define OFF_APT      20447232u   // 2097152  f16 apT4 [256 hq][1024 ba][4]
#define OFF_XP0      22544384u   //  532480  bf16 xp0 [2][130][1024] row-major
#define OFF_XP1      23076864u   //  532480  bf16 xp1 [2][130][1024] raw relu
#define OFF_Y2       23609344u   //  524288  bf16 y2 [256][1024]
#define OFF_BST1     24133632u   //    4096  f32 bstat1 [512][2]
#define OFF_BST2     24137728u   //    4096  f32 bstat2 [512][2]
#define OFF_LP       24141824u   // 2097152  f32 lp [4][256][512]
#define OFF_SG       26238976u   //   12288  f32 Sg3 [1024][3]
#define OFF_SB       26251264u   //   12288  f32 Sb3 [1024][3]
#define OFF_SGF      26263552u   //    4096  f32 SgF [1024]
#define OFF_SBF      26267648u   //    4096  f32 SbF [1024]

// ---------------------------------------------------------------------------
// prep: [0,1280) act cvt (xp0 row-major + textP/audioP fragment-packed);
// [1280,3328) w1 transpose -> fragment-packed topP/botP;
// [3328,4352) wc1 fragment-pack; 4352: zero pads + w2->f16.
// (wc2 + Sg/Sb moved to p2.)
// ---------------------------------------------------------------------------
__global__ __launch_bounds__(256) void prep_k(
    const float* __restrict__ text, const float* __restrict__ audio,
    const float* __restrict__ w1,
    const float* __restrict__ w1c, const float* __restrict__ w2,
    bf16_t* __restrict__ textP, bf16_t* __restrict__ xp0,
    bf16_t* __restrict__ audioP,
    bf16_t* __restrict__ topP, bf16_t* __restrict__ botP,
    bf16_t* __restrict__ wc1,
    bf16_t* __restrict__ xp1, f16_t* __restrict__ w2f)
{
    __shared__ float tile[32][33];
    const int bid = blockIdx.x;
    const int tid = threadIdx.x;
    if (bid < 1280) {
        const int e = (bid * 256 + tid) * 4;   // 1310720 total; h = 4*tid
        if (e < 262144) {
            float4 v = *(const float4*)&text[e];
            bf16x4 o; o[0] = (bf16_t)v.x; o[1] = (bf16_t)v.y; o[2] = (bf16_t)v.z; o[3] = (bf16_t)v.w;
            const int bt = e >> 10, h = e & 1023;
            const int b = bt >> 7, t = bt & 127;
            *(bf16x4*)&xp0[(size_t)(b * 130 + 1 + t) * 1024 + h] = o;
            const int h0 = h & ~7;             // even-thread h
            const int lane = (bt & 15) | (((h0 >> 3) & 3) << 4);
            bf16_t* ea = &textP[((size_t)((bt >> 4) * 32 + (h0 >> 5))) * 512 + lane * 8];
            pair_store16(ea, o, tid);
        } else {
            const int ea4 = e - 262144;
            float4 v = *(const float4*)&audio[ea4];
            bf16x4 o; o[0] = (bf16_t)v.x; o[1] = (bf16_t)v.y; o[2] = (bf16_t)v.z; o[3] = (bf16_t)v.w;
            const int ba = ea4 >> 10, h = ea4 & 1023;
            const int h0 = h & ~7;
            const int lane = (ba & 15) | (((h0 >> 3) & 3) << 4);
            bf16_t* ea = &audioP[((size_t)((ba >> 4) * 32 + (h0 >> 5))) * 512 + lane * 8];
            pair_store16(ea, o, tid);
        }
    } else if (bid < 3328) {
        const int b2 = bid - 1280;
        const int bx = b2 & 31, by = b2 >> 5;          // bx: d-blk(32), by: h-blk(64)
        const int tx = tid & 31, ty = tid >> 5;
        #pragma unroll
        for (int j = 0; j < 4; ++j)
            tile[ty + j * 8][tx] = w1[(size_t)(by * 32 + ty + j * 8) * 1024 + bx * 32 + tx];
        __syncthreads();
        if (tid < 128) {
            const int rbl = tid >> 6, lane = tid & 63;
            const int dl = rbl * 16 + (lane & 15);
            const int lkp = lane >> 4;
            bf16x8 v8;
            #pragma unroll
            for (int e2 = 0; e2 < 8; ++e2) v8[e2] = (bf16_t)tile[lkp * 8 + e2][dl];
            const int d = bx * 32 + dl;
            bf16_t* out = (by < 32) ? topP : botP;
            *(bf16x8*)&out[((size_t)((d >> 4) * 32 + (by & 31))) * 512 + lane * 8] = v8;
        }
    } else if (bid < 4352) {
        const int o = bid - 3328;                      // wc1 chan
        const int i0 = tid * 4;
        const float* src = w1c + (size_t)o * 3072 + tid * 12;
        float4 v0 = *(const float4*)&src[0];
        float4 v1 = *(const float4*)&src[4];
        float4 v2 = *(const float4*)&src[8];
        const float f[12] = {v0.x, v0.y, v0.z, v0.w, v1.x, v1.y, v1.z, v1.w, v2.x, v2.y, v2.z, v2.w};
        const int ip = i0 & ~7;                        // even-thread i0
        const int lane = (o & 15) | (((ip >> 3) & 3) << 4);
        #pragma unroll
        for (int r = 0; r < 3; ++r) {
            bf16x4 o4;
            #pragma unroll
            for (int j = 0; j < 4; ++j) o4[j] = (bf16_t)f[j * 3 + r];
            bf16_t* ea = &wc1[((size_t)(r * 2048 + (o >> 4) * 32 + (ip >> 5))) * 512 + lane * 8];
            pair_store16(ea, o4, tid);
        }
    } else {
        const int rowmap[4] = {0, 129, 130, 259};
        const int f = tid * 16;
        const int r = f >> 10, w = f & 1023;
        bf16x8 z8 = (bf16x8)(bf16_t)0.0f;
        bf16_t* p0 = xp0 + (size_t)rowmap[r] * 1024 + w;
        bf16_t* p1 = xp1 + (size_t)rowmap[r] * 1024 + w;
        *(bf16x8*)p0 = z8; *(bf16x8*)(p0 + 8) = z8;
        *(bf16x8*)p1 = z8; *(bf16x8*)(p1 + 8) = z8;
        float4 wv = *(const float4*)&w2[tid * 4];
        f16x4 wo; wo[0] = (f16_t)wv.x; wo[1] = (f16_t)wv.y; wo[2] = (f16_t)wv.z; wo[3] = (f16_t)wv.w;
        *(f16x4*)&w2f[tid * 4] = wo;
    }
}

// ---------------------------------------------------------------------------
// helpers
// ---------------------------------------------------------------------------
__device__ __forceinline__ float wave_red_add(float v) {
    #pragma unroll
    for (int off = 32; off > 0; off >>= 1) v += __shfl_xor(v, off);
    return v;
}

// Conv MFMA body (R21): weights fragment-packed (contiguous 1KB loads,
// issued BEFORE staging so HBM latency hides under the LDS staging loop);
// activations staged in padded LDS [34][264].
__device__ __forceinline__ void conv_body(
    const bf16_t* __restrict__ WcP, const bf16_t* __restrict__ xp,
    int by, int b, int tbase, int w, int l, bf16_t* Bs, int tid,
    f32x4& acc0, f32x4& acc1)
{
    const int lm = l & 15, lk = (l >> 4) * 8;
    const bf16_t* xrow = xp + (size_t)(b * 130 + tbase) * 1024;
    #pragma unroll 1
    for (int c = 0; c < 4; ++c) {
        __syncthreads();
        const int kc = c * 8 + w;
        const bf16_t* a0 = WcP + ((size_t)(by * 32 + kc)) * 512 + l * 8;
        v4i A0, A1, A2;
        GLD(A0, a0, 0);
        GLD(A1, a0 + 1048576, 0);
        GLD(A2, a0 + 2097152, 0);
        for (int idx = tid; idx < 1088; idx += 512) {
            const int row = idx >> 5, col = (idx & 31) * 8;
            *(v4i*)&Bs[row * 264 + col] =
                *(const v4i*)&xrow[(size_t)row * 1024 + c * 256 + col];
        }
        __syncthreads();
        const int cb = w * 32 + lk;
        bf16x8 b00 = *(const bf16x8*)&Bs[(lm + 0) * 264 + cb];
        bf16x8 b10 = *(const bf16x8*)&Bs[(lm + 16) * 264 + cb];
        bf16x8 b01 = *(const bf16x8*)&Bs[(lm + 1) * 264 + cb];
        bf16x8 b11 = *(const bf16x8*)&Bs[(lm + 17) * 264 + cb];
        bf16x8 b02 = *(const bf16x8*)&Bs[(lm + 2) * 264 + cb];
        bf16x8 b12 = *(const bf16x8*)&Bs[(lm + 18) * 264 + cb];
        WAITV(2);
        acc0 = __builtin_amdgcn_mfma_f32_16x16x32_bf16(as_bf16x8(A0), b00, acc0, 0, 0, 0);
        acc1 = __builtin_amdgcn_mfma_f32_16x16x32_bf16(as_bf16x8(A0), b10, acc1, 0, 0, 0);
        WAITV(1);
        acc0 = __builtin_amdgcn_mfma_f32_16x16x32_bf16(as_bf16x8(A1), b01, acc0, 0, 0, 0);
        acc1 = __builtin_amdgcn_mfma_f32_16x16x32_bf16(as_bf16x8(A1), b11, acc1, 0, 0, 0);
        WAITV(0);
        acc0 = __builtin_amdgcn_mfma_f32_16x16x32_bf16(as_bf16x8(A2), b02, acc0, 0, 0, 0);
        acc1 = __builtin_amdgcn_mfma_f32_16x16x32_bf16(as_bf16x8(A2), b12, acc1, 0, 0, 0);
    }
    __syncthreads();
}

// ---------------------------------------------------------------------------
// P2: [0,512) conv1; [512,768) tp gemm; [768,1792) ap gemm;
//     [1792,2304) wc2 fragment-pack (2 chans/block) + Sg/Sb/SgF/SbF.
// ---------------------------------------------------------------------------
__global__ __launch_bounds__(512) void p2_k(
    const bf16_t* __restrict__ wc1, const bf16_t* __restrict__ xp0,
    const float* __restrict__ d_b1, bf16_t* __restrict__ xp1,
    float* __restrict__ bstat1,
    const bf16_t* __restrict__ textP, const bf16_t* __restrict__ topP,
    const float* __restrict__ a_b1, f16_t* __restrict__ tp,
    const bf16_t* __restrict__ audioP, const bf16_t* __restrict__ botP,
    f16_t* __restrict__ apT4,
    const float* __restrict__ w2c, const float* __restrict__ g1,
    const float* __restrict__ b1g, bf16_t* __restrict__ wc2,
    float* __restrict__ Sg3, float* __restrict__ Sb3,
    float* __restrict__ SgF, float* __restrict__ SbF)
{
    __shared__ float smem[8448];
    __shared__ float sred[8], sredq[8];
    const int bid = blockIdx.x;
    const int tid = threadIdx.x;
    const int w = tid >> 6, l = tid & 63;
    const int lm = l & 15, lh = l >> 4;
    if (bid < 512) {
        const int bx = bid >> 6, by = bid & 63;
        const int bt0 = bx * 32, m0 = by * 16;
        const int b = bt0 >> 7, tbase = bt0 & 127;
        f32x4 acc0 = (f32x4)(0.0f), acc1 = (f32x4)(0.0f);
        conv_body(wc1, xp0, by, b, tbase, w, l, (bf16_t*)smem, tid, acc0, acc1);
        float* sl = smem + w * 528;
        #pragma unroll
        for (int r = 0; r < 4; ++r) {
            sl[(lh * 4 + r) * 33 + lm] = acc0[r];
            sl[(lh * 4 + r) * 33 + 16 + lm] = acc1[r];
        }
        __syncthreads();
        const int mm = tid >> 5, nn = tid & 31;  // chan-local, bt-local
        float v = 0.f;
        #pragma unroll
        for (int ww = 0; ww < 8; ++ww) v += smem[ww * 528 + mm * 33 + nn];
        v = fmaxf(v + d_b1[m0 + mm], 0.f);
        float s = wave_red_add(v), q = wave_red_add(v * v);
        if (l == 0) { sred[w] = s; sredq[w] = q; }
        xp1[(size_t)(b * 130 + 1 + tbase + nn) * 1024 + m0 + mm] = (bf16_t)v;
        __syncthreads();
        if (tid == 0) {
            float ts = 0.f, tq = 0.f;
            #pragma unroll
            for (int ww = 0; ww < 8; ++ww) { ts += sred[ww]; tq += sredq[ww]; }
            bstat1[bid * 2] = ts; bstat1[bid * 2 + 1] = tq;
        }
    } else if (bid < 1792) {
        // gemm 32x32 tile, 8-way K-split; fragment-packed operands.
        const bf16_t *At, *Bm;
        int d0, r0, is_tp;
        if (bid < 768) {
            const int unit = bid - 512;          // 256 units: 8 bt x 32 d
            d0 = (unit & 31) * 32; r0 = (unit >> 5) * 32;
            At = topP; Bm = textP; is_tp = 1;
        } else {
            const int unit = bid - 768;          // 1024 units: 32 a x 32 d
            d0 = (unit & 31) * 32; r0 = (unit >> 5) * 32;
            At = botP; Bm = audioP; is_tp = 0;
        }
        const int rb0 = d0 >> 4, rbB = r0 >> 4;
        const bf16_t* Ap0 = At + ((size_t)(rb0 * 32 + w * 4)) * 512 + l * 8;
        const bf16_t* Ap1 = Ap0 + 16384;
        const bf16_t* Bp0 = Bm + ((size_t)(rbB * 32 + w * 4)) * 512 + l * 8;
        const bf16_t* Bp1 = Bp0 + 16384;
        v4i qa0[4], qa1[4], qb0[4], qb1[4];
        GLD(qa0[0], Ap0,    0); GLD(qa1[0], Ap1,    0); GLD(qb0[0], Bp0,    0); GLD(qb1[0], Bp1,    0);
        GLD(qa0[1], Ap0, 1024); GLD(qa1[1], Ap1, 1024); GLD(qb0[1], Bp0, 1024); GLD(qb1[1], Bp1, 1024);
        GLD(qa0[2], Ap0, 2048); GLD(qa1[2], Ap1, 2048); GLD(qb0[2], Bp0, 2048); GLD(qb1[2], Bp1, 2048);
        GLD(qa0[3], Ap0, 3072); GLD(qa1[3], Ap1, 3072); GLD(qb0[3], Bp0, 3072); GLD(qb1[3], Bp1, 3072);
        f32x4 acc[2][2];
        #pragma unroll
        for (int mt = 0; mt < 2; ++mt)
            #pragma unroll
            for (int nt = 0; nt < 2; ++nt) acc[mt][nt] = (f32x4)(0.0f);
#define GMF(cc, n) \
        WAITV(n); \
        acc[0][0] = __builtin_amdgcn_mfma_f32_16x16x32_bf16(as_bf16x8(qa0[cc]), as_bf16x8(qb0[cc]), acc[0][0], 0, 0, 0); \
        acc[0][1] = __builtin_amdgcn_mfma_f32_16x16x32_bf16(as_bf16x8(qa0[cc]), as_bf16x8(qb1[cc]), acc[0][1], 0, 0, 0); \
        acc[1][0] = __builtin_amdgcn_mfma_f32_16x16x32_bf16(as_bf16x8(qa1[cc]), as_bf16x8(qb0[cc]), acc[1][0], 0, 0, 0); \
        acc[1][1] = __builtin_amdgcn_mfma_f32_16x16x32_bf16(as_bf16x8(qa1[cc]), as_bf16x8(qb1[cc]), acc[1][1], 0, 0, 0)
        GMF(0, 12); GMF(1, 8); GMF(2, 4); GMF(3, 0);
#undef GMF
        float* sl = smem + w * 1056;
        #pragma unroll
        for (int mt = 0; mt < 2; ++mt)
            #pragma unroll
            for (int nt = 0; nt < 2; ++nt)
                #pragma unroll
                for (int r = 0; r < 4; ++r)
                    sl[(mt * 16 + lh * 4 + r) * 33 + nt * 16 + lm] = acc[mt][nt][r];
        __syncthreads();
        const int m = tid >> 4, n2 = (tid & 15) * 2;     // d-local, row-local pair
        float v0 = 0.f, v1 = 0.f;
        #pragma unroll
        for (int ww = 0; ww < 8; ++ww) {
            v0 += smem[ww * 1056 + m * 33 + n2];
            v1 += smem[ww * 1056 + m * 33 + n2 + 1];
        }
        if (is_tp) {
            const float bb = a_b1[d0 + m];
            tp[(size_t)(r0 + n2) * 1024 + d0 + m] = (f16_t)(v0 + bb);
            tp[(size_t)(r0 + n2 + 1) * 1024 + d0 + m] = (f16_t)(v1 + bb);
        } else {
            const int h = d0 + m, hq = h >> 2, hr = h & 3;
            const int a0 = r0 + n2;
            const int bbk = a0 >> 9, al = a0 & 511;
            apT4[((size_t)hq * 1024 + bbk * 512 + al) * 4 + hr] = (f16_t)v0;
            apT4[((size_t)hq * 1024 + bbk * 512 + al + 1) * 4 + hr] = (f16_t)v1;
        }
    } else {
        // ---- wc2 fragment-pack + Sg/Sb/SgF/SbF (2 chans/block) ----------
        const int half = tid >> 8, t = tid & 255;
        const int o = (bid - 1792) * 2 + half;
        const int i0 = t * 4;
        const float* src = w2c + (size_t)o * 3072 + t * 12;
        float4 v0 = *(const float4*)&src[0];
        float4 v1 = *(const float4*)&src[4];
        float4 v2 = *(const float4*)&src[8];
        const float f[12] = {v0.x, v0.y, v0.z, v0.w, v1.x, v1.y, v1.z, v1.w, v2.x, v2.y, v2.z, v2.w};
        float4 gv = *(const float4*)&g1[i0];
        float4 bv = *(const float4*)&b1g[i0];
        const float g4[4] = {gv.x, gv.y, gv.z, gv.w};
        const float bb4[4] = {bv.x, bv.y, bv.z, bv.w};
        const int ip = i0 & ~7;
        const int lane = (o & 15) | (((ip >> 3) & 3) << 4);
        float sgr[3] = {0.f, 0.f, 0.f}, sbr[3] = {0.f, 0.f, 0.f};
        #pragma unroll
        for (int r = 0; r < 3; ++r) {
            bf16x4 o4;
            #pragma unroll
            for (int j = 0; j < 4; ++j) {
                const float wv = f[j * 3 + r];
                const float ws = wv * g4[j];
                sgr[r] += ws;
                sbr[r] += wv * bb4[j];
                o4[j] = (bf16_t)ws;
            }
            bf16_t* ea = &wc2[((size_t)(r * 2048 + (o >> 4) * 32 + (ip >> 5))) * 512 + lane * 8];
            pair_store16(ea, o4, t);
        }
        #pragma unroll
        for (int off = 32; off > 0; off >>= 1) {
            #pragma unroll
            for (int r = 0; r < 3; ++r) {
                sgr[r] += __shfl_xor(sgr[r], off);
                sbr[r] += __shfl_xor(sbr[r], off);
            }
        }
        float* red = smem + half * 32;
        const int wid = t >> 6, lane2 = t & 63;
        if (lane2 == 0) {
            #pragma unroll
            for (int r = 0; r < 3; ++r) {
                red[wid * 6 + r] = sgr[r];
                red[wid * 6 + 3 + r] = sbr[r];
            }
        }
        __syncthreads();
        if (t < 6) {
            const float v = red[t] + red[6 + t] + red[12 + t] + red[18 + t];
            if (t < 3) Sg3[o * 3 + t] = v;
            else       Sb3[o * 3 + t - 3] = v;
            red[24 + t] = v;
        }
        __syncthreads();
        if (t == 0)      SgF[o] = red[24] + red[25] + red[26];
        else if (t == 1) SbF[o] = red[27] + red[28] + red[29];
    }
}

// reduce 256 (s,q) pairs for batch b from bstat (block-level, 512 threads).
__device__ __forceinline__ void reduce_bstat(
    const float* __restrict__ bstat, int b, int tid,
    float* sr, float* sq, float& mu, float& rsig)
{
    const int lane = tid & 63, wid = tid >> 6;
    float s = 0.f, q = 0.f;
    if (tid < 256) {
        float2 v = ((const float2*)bstat)[b * 256 + tid];
        s = v.x; q = v.y;
    }
    #pragma unroll
    for (int off = 32; off > 0; off >>= 1) {
        s += __shfl_xor(s, off);
        q += __shfl_xor(q, off);
    }
    if (lane == 0) { sr[wid] = s; sq[wid] = q; }
    __syncthreads();
    float ts = 0.f, tq = 0.f;
    #pragma unroll
    for (int i = 0; i < 8; ++i) { ts += sr[i]; tq += sq[i]; }
    const float cnt = 131072.f;
    mu = ts / cnt;
    const float var = tq / cnt - mu * mu;
    rsig = rsqrtf(var + EPSV);
}

// ---------------------------------------------------------------------------
// P3: blocks [0,512) conv2 tiles (GN1 folded); [512,768) logits blocks.
// ---------------------------------------------------------------------------
__device__ __forceinline__ float dot2_acc(f16x2 x, f16x2 w, float acc) {
#if __has_builtin(__builtin_amdgcn_fdot2)
    return __builtin_amdgcn_fdot2(x, w, acc, false);
#else
    return acc + (float)x[0] * (float)w[0] + (float)x[1] * (float)w[1];
#endif
}

__global__ __launch_bounds__(512) void p3_k(
    const bf16_t* __restrict__ wc2, const bf16_t* __restrict__ xp1,
    const float* __restrict__ d_b2, bf16_t* __restrict__ y2,
    float* __restrict__ bstat2, const float* __restrict__ bstat1,
    const float* __restrict__ SgF, const float* __restrict__ SbF,
    const float* __restrict__ Sg3, const float* __restrict__ Sb3,
    const f16_t* __restrict__ tp, const f16_t* __restrict__ apT4,
    const f16_t* __restrict__ w2f, float* __restrict__ lp)
{
    __shared__ float smem[4608];                 // conv: Bs bf16[34][264] then [8][16][33]
    __shared__ float sred[8], sredq[8], sr[8], sq[8];
    const int bid = blockIdx.x;
    const int tid = threadIdx.x;
    if (bid < 512) {
        const int w = tid >> 6, l = tid & 63;
        const int lm = l & 15, lh = l >> 4;
        const int bx = bid >> 6, by = bid & 63;
        const int bt0 = bx * 32, m0 = by * 16;
        const int b = bt0 >> 7, tbase = bt0 & 127;
        f32x4 acc0 = (f32x4)(0.0f), acc1 = (f32x4)(0.0f);
        conv_body(wc2, xp1, by, b, tbase, w, l, (bf16_t*)smem, tid, acc0, acc1);
        float* sl = smem + w * 528;
        #pragma unroll
        for (int r = 0; r < 4; ++r) {
            sl[(lh * 4 + r) * 33 + lm] = acc0[r];
            sl[(lh * 4 + r) * 33 + 16 + lm] = acc1[r];
        }
        __syncthreads();
        const int mm = tid >> 5, nn = tid & 31;
        float vraw = 0.f;
        #pragma unroll
        for (int ww = 0; ww < 8; ++ww) vraw += smem[ww * 528 + mm * 33 + nn];
        float mu, rsig;
        reduce_bstat(bstat1, b, tid, sr, sq, mu, rsig);   // has its own barrier
        const int o = m0 + mm, tloc = tbase + nn;
        float sg = SgF[o], sb = SbF[o];
        if (tloc == 0)   { sg -= Sg3[o * 3];     sb -= Sb3[o * 3]; }
        if (tloc == 127) { sg -= Sg3[o * 3 + 2]; sb -= Sb3[o * 3 + 2]; }
        float v = fmaxf(rsig * vraw + sb - mu * rsig * sg + d_b2[o], 0.f);
        float s = wave_red_add(v), q = wave_red_add(v * v);
        if ((tid & 63) == 0) { sred[tid >> 6] = s; sredq[tid >> 6] = q; }
        y2[(size_t)(b * 128 + tloc) * 1024 + o] = (bf16_t)v;
        __syncthreads();
        if (tid == 0) {
            float ts = 0.f, tq = 0.f;
            #pragma unroll
            for (int ww = 0; ww < 8; ++ww) { ts += sred[ww]; tq += sredq[ww]; }
            bstat2[bid * 2] = ts; bstat2[bid * 2 + 1] = tq;
        }
    } else {
        const int lb = bid - 512;                       // 256 blocks
        const int hc = lb >> 6, btp = lb & 63;
        const int bt0 = btp * 4;
        const int b = bt0 >> 7;
        const int a = tid;                              // 0..511
        const f16_t* tpr = tp + (size_t)bt0 * 1024 + hc * 256;   // wave-uniform
        const f16_t* w2r = w2f + hc * 256;
        const f16_t* apc = apT4 + ((size_t)(hc * 64) * 1024 + b * 512 + a) * 4;
        float acc[4] = {0.f, 0.f, 0.f, 0.f};
        const f16x2 zero = (f16x2)(f16_t)0.0f;
#define L_A0(i) (*(const f16x4*)(apc + (size_t)(2 * (i)) * 4096))
#define L_A1(i) (*(const f16x4*)(apc + (size_t)(2 * (i) + 1) * 4096))
        constexpr int PF = 4;
        f16x4 pa[PF], pb[PF];
        #pragma unroll
        for (int i = 0; i < PF; ++i) { pa[i] = L_A0(i); pb[i] = L_A1(i); }
        #pragma unroll
        for (int i = 0; i < 32; ++i) {                  // hq pair per iter
            const int sl = i % PF;
            const int hq = 2 * i;
            f16x4 a0 = pa[sl], a1 = pb[sl];
            f16x4 w0 = *(const f16x4*)&w2r[hq * 4];
            f16x4 w1 = *(const f16x4*)&w2r[hq * 4 + 4];
            #pragma unroll
            for (int r = 0; r < 4; ++r) {
                f16x4 t0 = *(const f16x4*)&tpr[r * 1024 + hq * 4];
                f16x4 t1 = *(const f16x4*)&tpr[r * 1024 + hq * 4 + 4];
                f16x2 p;
                p = __builtin_elementwise_max((f16x2){t0[0] + a0[0], t0[1] + a0[1]}, zero);
                acc[r] = dot2_acc(p, (f16x2){w0[0], w0[1]}, acc[r]);
                p = __builtin_elementwise_max((f16x2){t0[2] + a0[2], t0[3] + a0[3]}, zero);
                acc[r] = dot2_acc(p, (f16x2){w0[2], w0[3]}, acc[r]);
                p = __builtin_elementwise_max((f16x2){t1[0] + a1[0], t1[1] + a1[1]}, zero);
                acc[r] = dot2_acc(p, (f16x2){w1[0], w1[1]}, acc[r]);
                p = __builtin_elementwise_max((f16x2){t1[2] + a1[2], t1[3] + a1[3]}, zero);
                acc[r] = dot2_acc(p, (f16x2){w1[2], w1[3]}, acc[r]);
            }
            const int nx = i + PF;
            if (nx < 32) { pa[sl] = L_A0(nx); pb[sl] = L_A1(nx); }
        }
#undef L_A0
#undef L_A1
        float* dst = lp + (size_t)(hc * 256 + bt0) * 512 + a;
        #pragma unroll
        for (int r = 0; r < 4; ++r) dst[(size_t)r * 512] = acc[r];
    }
}

// ---------------------------------------------------------------------------
// combine: blocks [0,256): softmax; [256,288): conv3 + GN2 + softplus.
// ---------------------------------------------------------------------------
__global__ __launch_bounds__(512) void combine_k(
    const float* __restrict__ lp, const float* __restrict__ b2,
    const bf16_t* __restrict__ y2, const float* __restrict__ bstat2,
    const float* __restrict__ g, const float* __restrict__ bet,
    const float* __restrict__ w3, const float* __restrict__ b3,
    float* __restrict__ out)
{
    __shared__ float redm[8], redsum[8];
    const int bid = blockIdx.x;
    const int tid = threadIdx.x;
    if (bid < 256) {
        const int bt = bid, t = bt & 127;
        const int a = tid;
        const int lane = a & 63, wid = a >> 6;
        const size_t base = (size_t)bt * 512 + a;
        float v = lp[base] + lp[131072 + base] + lp[262144 + base] + lp[393216 + base];
        v += b2[0] - 0.1f * fabsf((float)a - 4.0f * (float)t);
        float m = v;
        #pragma unroll
        for (int off = 32; off > 0; off >>= 1) m = fmaxf(m, __shfl_xor(m, off));
        if (lane == 0) redm[wid] = m;
        __syncthreads();
        float M = redm[0];
        #pragma unroll
        for (int i = 1; i < 8; ++i) M = fmaxf(M, redm[i]);
        const float e = expf(v - M);
        float s = e;
        #pragma unroll
        for (int off = 32; off > 0; off >>= 1) s += __shfl_xor(s, off);
        if (lane == 0) redsum[wid] = s;
        __syncthreads();
        float S = redsum[0];
        #pragma unroll
        for (int i = 1; i < 8; ++i) S += redsum[i];
        out[(size_t)bt * 512 + a] = e * (1.0f / S);
    } else {
        const int cb = bid - 256;              // 0..31, bt [cb*8, cb*8+8)
        const int b = (cb * 8) >> 7;
        float mu, rsig;
        reduce_bstat(bstat2, b, tid, redm, redsum, mu, rsig);
        const int lane = tid & 63, w = tid >> 6;
        const int bt = cb * 8 + w;
        const bf16_t* row = y2 + (size_t)bt * 1024 + lane * 16;
        float s1 = 0.f, s2 = 0.f, s3 = 0.f;
        #pragma unroll
        for (int c = 0; c < 2; ++c) {
            bf16x8 yv = *(const bf16x8*)(row + c * 8);
            #pragma unroll
            for (int j = 0; j < 8; ++j) {
                const int i = lane * 16 + c * 8 + j;
                const float gw = g[i] * w3[i];
                s1 += gw * (float)yv[j];
                s2 += gw;
                s3 += bet[i] * w3[i];
            }
        }
        #pragma unroll
        for (int off = 32; off > 0; off >>= 1) {
            s1 += __shfl_xor(s1, off);
            s2 += __shfl_xor(s2, off);
            s3 += __shfl_xor(s3, off);
        }
        if (lane == 0) {
            const float t = rsig * (s1 - mu * s2) + s3 + b3[0];
            out[131072 + bt] = fmaxf(t, 0.f) + log1pf(expf(-fabsf(t)));
        }
    }
}

extern "C" void kernel_launch(void* const* d_in, const int* in_sizes, int n_in,
                              void* d_out, int out_size, void* d_ws, size_t ws_size,
                              hipStream_t stream) {
    const float* text   = (const float*)d_in[0];
    const float* audio  = (const float*)d_in[1];
    const float* a_w1   = (const float*)d_in[2];
    const float* a_b1   = (const float*)d_in[3];
    const float* a_w2   = (const float*)d_in[4];
    const float* a_b2   = (const float*)d_in[5];
    const float* d_w1   = (const float*)d_in[6];
    const float* d_b1   = (const float*)d_in[7];
    const float* gn1_g  = (const float*)d_in[8];
    const float* gn1_b  = (const float*)d_in[9];
    const float* d_w2   = (const float*)d_in[10];
    const float* d_b2   = (const float*)d_in[11];
    const float* gn2_g  = (const float*)d_in[12];
    const float* gn2_b  = (const float*)d_in[13];
    const float* d_w3   = (const float*)d_in[14];
    const float* d_b3   = (const float*)d_in[15];

    char* ws = (char*)d_ws;
    float* outf = (float*)d_out;

    bf16_t* textP    = (bf16_t*)(ws + OFF_TEXTP);
    bf16_t* audioP   = (bf16_t*)(ws + OFF_AUDIOP);
    bf16_t* topP     = (bf16_t*)(ws + OFF_W1TOP);
    bf16_t* botP     = (bf16_t*)(ws + OFF_W1BOT);
    bf16_t* wc1      = (bf16_t*)(ws + OFF_WC1);
    bf16_t* wc2      = (bf16_t*)(ws + OFF_WC2);
    f16_t*  tp       = (f16_t*) (ws + OFF_TP);
    f16_t*  w2f      = (f16_t*) (ws + OFF_W2F);
    f16_t*  apT4     = (f16_t*) (ws + OFF_APT);
    bf16_t* xp0      = (bf16_t*)(ws + OFF_XP0);
    bf16_t* xp1      = (bf16_t*)(ws + OFF_XP1);
    bf16_t* y2       = (bf16_t*)(ws + OFF_Y2);
    float*  bstat1   = (float*) (ws + OFF_BST1);
    float*  bstat2   = (float*) (ws + OFF_BST2);
    float*  lp       = (float*) (ws + OFF_LP);
    float*  Sg3      = (float*) (ws + OFF_SG);
    float*  Sb3      = (float*) (ws + OFF_SB);
    float*  SgFp     = (float*) (ws + OFF_SGF);
    float*  SbFp     = (float*) (ws + OFF_SBF);

    // 1: prep (act pack, w1 pack, wc1 pack, pads, w2f) — wc2 moved to p2
    prep_k<<<dim3(4353), 256, 0, stream>>>(text, audio, a_w1, d_w1, a_w2,
                                           textP, xp0, audioP, topP, botP,
                                           wc1, xp1, w2f);
    // 2: conv1 (512) ∥ tp gemm (256) ∥ ap gemm (1024) ∥ wc2-pack (512)
    p2_k<<<dim3(2304), 512, 0, stream>>>(wc1, xp0, d_b1, xp1, bstat1,
                                         textP, topP, a_b1, tp,
                                         audioP, botP, apT4,
                                         d_w2, gn1_g, gn1_b, wc2,
                                         Sg3, Sb3, SgFp, SbFp);
    // 3: conv2 (512, GN1 folded) ∥ logits (256) — 768 x 512 thr
    p3_k<<<dim3(768), 512, 0, stream>>>(wc2, xp1, d_b2, y2, bstat2, bstat1,
                                        SgFp, SbFp, Sg3, Sb3, tp, apT4, w2f, lp);
    // 4: combine+softmax -> alignment; conv3+GN2(reduced)+softplus -> durations
    combine_k<<<dim3(288), 512, 0, stream>>>(lp, a_b2, y2, bstat2,
                                             gn2_g, gn2_b, d_w3, d_b3, outf);
}